// Round 11
// baseline (309.633 us; speedup 1.0000x reference)
//
#include <hip/hip_runtime.h>
#include <hip/hip_bf16.h>
#include <math.h>

typedef __attribute__((ext_vector_type(8))) short short8;
typedef __attribute__((ext_vector_type(4))) short short4v;
typedef __attribute__((ext_vector_type(4))) float f32x4;
typedef unsigned short ushort_t;

// scale(1/sqrt(128)) * log2(e): folded into Q so attn softmax uses exp2 with no mults
#define QK_LOG2E_SCALE 0.1275274059009601f

__device__ __forceinline__ ushort_t f2bf(float f) {
    union { float f; unsigned u; } v; v.f = f;
    unsigned r = v.u + 0x7FFF + ((v.u >> 16) & 1);
    return (ushort_t)(r >> 16);
}

// ---- fused convert: x|wq|wk|wv|wo -> bf16, plus packed float2 (cos,sin) table ----
__global__ void cvt_all(const float* __restrict__ x,
                        const float* __restrict__ w0, const float* __restrict__ w1,
                        const float* __restrict__ w2, const float* __restrict__ w3,
                        const float* __restrict__ fc, const float* __restrict__ fs,
                        ushort_t* __restrict__ dst, float2* __restrict__ fcs,
                        int md8, int dd8, int npair4) {
    int i = blockIdx.x * blockDim.x + threadIdx.x;
    int stride = gridDim.x * blockDim.x;
    const int total0 = md8 + 4 * dd8;
    const int total = total0 + npair4;
    for (; i < total; i += stride) {
        if (i < total0) {
            const float* src;
            long off;
            if (i < md8) { src = x; off = i; }
            else {
                int j = i - md8;
                int which = j / dd8;
                off = j - (long)which * dd8;
                src = (which == 0) ? w0 : (which == 1) ? w1 : (which == 2) ? w2 : w3;
            }
            const float4* s = reinterpret_cast<const float4*>(src) + off * 2;
            float4 a = s[0], b = s[1];
            short8 o;
            o[0] = (short)f2bf(a.x); o[1] = (short)f2bf(a.y);
            o[2] = (short)f2bf(a.z); o[3] = (short)f2bf(a.w);
            o[4] = (short)f2bf(b.x); o[5] = (short)f2bf(b.y);
            o[6] = (short)f2bf(b.z); o[7] = (short)f2bf(b.w);
            reinterpret_cast<short8*>(dst)[i] = o;
        } else {
            int j = i - total0;
            float4 c4 = reinterpret_cast<const float4*>(fc)[j];
            float4 s4 = reinterpret_cast<const float4*>(fs)[j];
            float2* o = fcs + (long)j * 4;
            o[0] = make_float2(c4.x, s4.x);
            o[1] = make_float2(c4.y, s4.y);
            o[2] = make_float2(c4.z, s4.z);
            o[3] = make_float2(c4.w, s4.w);
        }
    }
}

// ============ 128x256 2-phase-per-K-tile GEMM (QKV): BK=64, 8 waves, counted vmcnt ============
// Grid 768 blocks = exactly 3 generations at 1 block/CU -> ZERO idle CUs (was 384 = 1.5 gen).
// LDS 96KB: A 2buf x [128][64], B 2buf x [256][64], XOR-swizzled 16B slots (0 conflicts proven).
// Per-wave output 64x64 = acc[4][4]. 6 loads/K-tile; vmcnt(6) end-of-tile (never 0 mid-loop).
// Stage placement: A(U+2) in P2 pre-barrier (A[buf] reads completed at P1's lgkm, all waves past
// P1 ENDBAR); B(U+2) after P2's MFMA (B[buf] reads completed at P2's lgkm) — proven P4 pattern.
// Epilogue fused: RoPE(+QK_LOG2E_SCALE fold on Q) for Q/K, transposed store for V.
__global__ __launch_bounds__(512, 2) void gemm256_qkv(const ushort_t* __restrict__ A,
                                                      const ushort_t* __restrict__ Bw,
                                                      ushort_t* __restrict__ Cout,
                                                      ushort_t* __restrict__ Vt,
                                                      const float2* __restrict__ fcs,
                                                      int M, int N, int K) {
    extern __shared__ __align__(16) ushort_t lds[];
    ushort_t* As = lds;              // 16384 elems (32KB)
    ushort_t* Bs = lds + 16384;      // 32768 elems (64KB)
    const int t = threadIdx.x;
    const int wid = t >> 6, lane = t & 63;
    const int wr = wid >> 2, wc = wid & 3;     // 2 row-waves x 4 col-waves
    const int lr = lane & 15, lg = lane >> 4;

    const int ntc = N >> 8;                     // 24 col-tiles (BN=256)
    const int nwg = (M >> 7) * ntc;             // 32*24 = 768
    const int bid = blockIdx.y * gridDim.x + blockIdx.x;
    const int cpx = nwg >> 3;
    const int swz = (bid & 7) * cpx + (bid >> 3);
    const int m0 = (swz / ntc) * 128, n0 = (swz % ntc) * 256;

    f32x4 acc[4][4] = {};

    const int r0 = t >> 3;
    const int c0 = (t & 7) ^ (r0 & 7);
    const ushort_t* gA = A + (long)(m0 + r0) * K + c0 * 8;
    const ushort_t* gB = Bw + (long)(n0 + r0) * K + c0 * 8;

    int aoffE[2];
    aoffE[0] = lr * 64 + (((0 + lg) ^ (lr & 7)) << 3);
    aoffE[1] = lr * 64 + (((4 + lg) ^ (lr & 7)) << 3);

    const int nt = K >> 6;   // 32 (even)

#define STAGE_A(X) do { const int p_ = (X) & 1;                                                \
    __builtin_amdgcn_global_load_lds((const __attribute__((address_space(1))) unsigned int*)   \
        (gA + (X) * 64),                                                                       \
        (__attribute__((address_space(3))) unsigned int*)(As + p_ * 8192 + t * 8), 16, 0, 0);  \
    __builtin_amdgcn_global_load_lds((const __attribute__((address_space(1))) unsigned int*)   \
        (gA + (long)64 * K + (X) * 64),                                                        \
        (__attribute__((address_space(3))) unsigned int*)(As + p_ * 8192 + 4096 + t * 8), 16, 0, 0); } while (0)

#define STAGE_B(X) do { const int p_ = (X) & 1;                                                \
    _Pragma("unroll")                                                                          \
    for (int j_ = 0; j_ < 4; ++j_)                                                             \
        __builtin_amdgcn_global_load_lds((const __attribute__((address_space(1))) unsigned int*) \
            (gB + (long)(j_ * 64) * K + (X) * 64),                                             \
            (__attribute__((address_space(3))) unsigned int*)(Bs + p_ * 16384 + j_ * 4096 + t * 8), 16, 0, 0); } while (0)

#define MIDSYNC() do {                                             \
    asm volatile("" ::: "memory");                                 \
    __builtin_amdgcn_s_barrier();                                  \
    asm volatile("s_waitcnt lgkmcnt(0)" ::: "memory");             \
    __builtin_amdgcn_sched_barrier(0); } while (0)

#define ENDBAR() do {                                              \
    asm volatile("" ::: "memory");                                 \
    __builtin_amdgcn_s_barrier(); } while (0)

#define MFMA_Q(BCOL, BR) do {                                      \
    __builtin_amdgcn_s_setprio(1);                                 \
    _Pragma("unroll")                                              \
    for (int ks = 0; ks < 2; ++ks)                                 \
        _Pragma("unroll")                                          \
        for (int m = 0; m < 4; ++m)                                \
            _Pragma("unroll")                                      \
            for (int n = 0; n < 2; ++n)                            \
                acc[m][(BCOL) + n] =                               \
                    __builtin_amdgcn_mfma_f32_16x16x32_bf16(ar[m][ks], (BR)[n][ks], acc[m][(BCOL) + n], 0, 0, 0); \
    __builtin_amdgcn_s_setprio(0); } while (0)

#define KTILE(U, BUF) do {                                                                     \
    const int Asb = (BUF) * 8192 + wr * 4096;                                                  \
    const int Bcb = (BUF) * 16384 + wc * 4096;                                                 \
    /* P1: read A + B-n01; MFMA n01 */                                                         \
    _Pragma("unroll")                                                                          \
    for (int m = 0; m < 4; ++m)                                                                \
        _Pragma("unroll")                                                                      \
        for (int ks = 0; ks < 2; ++ks)                                                         \
            ar[m][ks] = *reinterpret_cast<const short8*>(&As[Asb + m * 1024 + aoffE[ks]]);     \
    _Pragma("unroll")                                                                          \
    for (int n = 0; n < 2; ++n)                                                                \
        _Pragma("unroll")                                                                      \
        for (int ks = 0; ks < 2; ++ks)                                                         \
            br0[n][ks] = *reinterpret_cast<const short8*>(&Bs[Bcb + n * 1024 + aoffE[ks]]);    \
    MIDSYNC();                                                                                 \
    MFMA_Q(0, br0);                                                                            \
    ENDBAR();                                                                                  \
    /* P2: read B-n23; stage A(U+2); MFMA n23; stage B(U+2); vmcnt; barrier */                 \
    _Pragma("unroll")                                                                          \
    for (int n = 0; n < 2; ++n)                                                                \
        _Pragma("unroll")                                                                      \
        for (int ks = 0; ks < 2; ++ks)                                                         \
            br1[n][ks] = *reinterpret_cast<const short8*>(&Bs[Bcb + 2048 + n * 1024 + aoffE[ks]]); \
    if ((U) + 2 < nt) STAGE_A((U) + 2);                                                        \
    MIDSYNC();                                                                                 \
    MFMA_Q(2, br1);                                                                            \
    if ((U) + 2 < nt) STAGE_B((U) + 2);                                                        \
    asm volatile("" ::: "memory");                                                             \
    if ((U) < nt - 2) {                                                                        \
        asm volatile("s_waitcnt vmcnt(6)" ::: "memory");                                       \
    } else if ((U) == nt - 2) {                                                                \
        asm volatile("s_waitcnt vmcnt(0)" ::: "memory");                                       \
    }                                                                                          \
    __builtin_amdgcn_s_barrier(); } while (0)

    // prologue: tiles 0 and 1 fully staged (12 loads); wait tile 0 (6 newest in flight)
    STAGE_A(0); STAGE_B(0); STAGE_A(1); STAGE_B(1);
    asm volatile("s_waitcnt vmcnt(6)" ::: "memory");
    __builtin_amdgcn_s_barrier();

    short8 ar[4][2], br0[2][2], br1[2][2];

    for (int U = 0; U < nt; U += 2) {
        KTILE(U, 0);
        KTILE(U + 1, 1);
    }
#undef KTILE
#undef MFMA_Q
#undef ENDBAR
#undef MIDSYNC
#undef STAGE_A
#undef STAGE_B

    // ---- fused epilogue: rope(Q*SC)/rope(K) head-packed; V transposed ----
    const int S = 2048;
    #pragma unroll
    for (int m = 0; m < 4; ++m) {
        #pragma unroll
        for (int n = 0; n < 4; ++n) {
            const int col = n0 + wc * 64 + n * 16 + lr;
            const int which = col >> 11;          // block-uniform (2048 % 256 == 0)
            const int h = (col >> 7) & 15;
            const int d = col & 127;
            const int rowb = m0 + wr * 64 + m * 16 + lg * 4;
            const int bb = rowb >> 11;
            const int sb = rowb & 2047;
            if (which == 2) {
                short4v o;
                #pragma unroll
                for (int r = 0; r < 4; ++r) o[r] = (short)f2bf(acc[m][n][r]);
                *reinterpret_cast<short4v*>(Vt + ((long)(bb * 16 + h) * 128 + d) * S + sb) = o;
            } else {
                const int i0 = d >> 1;
                const float qs = (which == 0) ? QK_LOG2E_SCALE : 1.0f;
                #pragma unroll
                for (int r = 0; r < 4; ++r) {
                    const int s = sb + r;
                    float v = acc[m][n][r];
                    float p = __shfl_xor(v, 1);
                    float2 cs = fcs[(long)s * 64 + i0];
                    float o = (lr & 1) ? (p * cs.y + v * cs.x) : (v * cs.x - p * cs.y);
                    Cout[(long)which * M * 2048 + (((long)(bb * 16 + h)) * 2048 + s) * 128 + d] = f2bf(o * qs);
                }
            }
        }
    }
}

// ---------------- GEMM NT 128x128 (proven 2-phase dbuf) — used for wo ----------------
__global__ __launch_bounds__(256) void gemm_nt_f32(const ushort_t* __restrict__ A,
                                                   const ushort_t* __restrict__ Bw,
                                                   float* __restrict__ Cout,
                                                   int M, int N, int K) {
    __shared__ __align__(16) ushort_t As[2 * 128 * 32];
    __shared__ __align__(16) ushort_t Bs[2 * 128 * 32];
    const int t = threadIdx.x;
    const int wid = t >> 6, lane = t & 63;
    const int wm = wid >> 1, wn = wid & 1;
    const int lr = lane & 15, lg = lane >> 4;

    const int ntc = N >> 7;
    const int nwg = (M >> 7) * ntc;
    const int bid = blockIdx.y * gridDim.x + blockIdx.x;
    const int cpx = nwg >> 3;
    const int swz = (bid & 7) * cpx + (bid >> 3);
    const int m0 = (swz / ntc) * 128, n0 = (swz % ntc) * 128;

    f32x4 acc[4][4] = {};

    const int sh0 = wid * 1024 + lane * 8;
    const int sh1 = sh0 + 512;
    const int r0 = sh0 >> 5, c0 = sh0 & 31;
    const int r1 = sh1 >> 5, c1 = sh1 & 31;

    const ushort_t* gA0 = A + (long)(m0 + r0) * K + c0;
    const ushort_t* gA1 = A + (long)(m0 + r1) * K + c1;
    const ushort_t* gB0 = Bw + (long)(n0 + r0) * K + c0;
    const ushort_t* gB1 = Bw + (long)(n0 + r1) * K + c1;

    auto stage = [&](int k0, int nb) {
        ushort_t* as = As + nb * 4096;
        ushort_t* bs = Bs + nb * 4096;
        __builtin_amdgcn_global_load_lds((const __attribute__((address_space(1))) unsigned int*)(gA0 + k0),
                                         (__attribute__((address_space(3))) unsigned int*)(as + sh0), 16, 0, 0);
        __builtin_amdgcn_global_load_lds((const __attribute__((address_space(1))) unsigned int*)(gA1 + k0),
                                         (__attribute__((address_space(3))) unsigned int*)(as + sh1), 16, 0, 0);
        __builtin_amdgcn_global_load_lds((const __attribute__((address_space(1))) unsigned int*)(gB0 + k0),
                                         (__attribute__((address_space(3))) unsigned int*)(bs + sh0), 16, 0, 0);
        __builtin_amdgcn_global_load_lds((const __attribute__((address_space(1))) unsigned int*)(gB1 + k0),
                                         (__attribute__((address_space(3))) unsigned int*)(bs + sh1), 16, 0, 0);
    };

    const int nt = K >> 5;
    stage(0, 0);
    __syncthreads();
    int cur = 0;

    for (int ti = 0; ti < nt; ++ti) {
        if (ti + 1 < nt) stage((ti + 1) << 5, cur ^ 1);
        const ushort_t* as = As + cur * 4096;
        const ushort_t* bs = Bs + cur * 4096;
        short8 af[4], bfr[4];
        #pragma unroll
        for (int m = 0; m < 4; ++m)
            af[m] = *reinterpret_cast<const short8*>(&as[(wm * 64 + m * 16 + lr) * 32 + lg * 8]);
        #pragma unroll
        for (int n = 0; n < 4; ++n)
            bfr[n] = *reinterpret_cast<const short8*>(&bs[(wn * 64 + n * 16 + lr) * 32 + lg * 8]);
        #pragma unroll
        for (int m = 0; m < 4; ++m)
            #pragma unroll
            for (int n = 0; n < 4; ++n)
                acc[m][n] = __builtin_amdgcn_mfma_f32_16x16x32_bf16(af[m], bfr[n], acc[m][n], 0, 0, 0);
        __syncthreads();
        cur ^= 1;
    }

    #pragma unroll
    for (int m = 0; m < 4; ++m) {
        #pragma unroll
        for (int n = 0; n < 4; ++n) {
            const int col = n0 + wn * 64 + n * 16 + lr;
            #pragma unroll
            for (int r = 0; r < 4; ++r) {
                const int row = m0 + wm * 64 + m * 16 + lg * 4 + r;
                Cout[(long)row * N + col] = acc[m][n][r];
            }
        }
    }
}

// ---------------- causal flash attention (round-10 structure; exp2 softmax, Pl pad 80) ----------------
__global__ __launch_bounds__(256, 3) void attn_kernel(const ushort_t* __restrict__ Qp,
                                                      const ushort_t* __restrict__ Kp,
                                                      const ushort_t* __restrict__ Vtg,
                                                      ushort_t* __restrict__ O,
                                                      int S, int H) {
    __shared__ __align__(16) ushort_t Ks[64 * 128];   // linear, XOR-swizzled 16B slots
    __shared__ __align__(16) ushort_t Vs[128 * 64];   // linear, XOR-swizzled 16B slots
    __shared__ __align__(16) ushort_t Pl[4][16][80];  // pad 80: write rows land on disjoint banks
    const int t = threadIdx.x, wid = t >> 6, lane = t & 63;
    const int lr = lane & 15, lg = lane >> 4;
    const int bh = blockIdx.y;
    const int b = bh / H, h = bh % H;
    const ushort_t* Qh = Qp + (long)bh * S * 128;
    const ushort_t* Kh = Kp + (long)bh * S * 128;
    const ushort_t* Vth = Vtg + (long)bh * 128 * S;
    const int nq = S / 64;

    const int ksr = t >> 2;
    const int vsr = t & 127;
    const int vsc = (t >> 7) * 32;

    for (int qsel = 0; qsel < 2; ++qsel) {
        const int qt = qsel ? (nq - 1 - blockIdx.x) : blockIdx.x;
        const int qb0 = qt * 64;

        const int qrow = qb0 + wid * 16 + lr;
        short8 qf[4];
        #pragma unroll
        for (int kk = 0; kk < 4; ++kk)
            qf[kk] = *reinterpret_cast<const short8*>(Qh + (long)qrow * 128 + kk * 32 + lg * 8);

        f32x4 oacc[8] = {};
        float mrow[4], lsum[4];
        #pragma unroll
        for (int r = 0; r < 4; ++r) { mrow[r] = -INFINITY; lsum[r] = 0.f; }

        const int nkt = qt + 1;

        short8 kreg[4], vreg[4];
        {
            const ushort_t* kgp = Kh + t * 32;
            const ushort_t* vgp = Vth + (long)vsr * S + vsc;
            #pragma unroll
            for (int j = 0; j < 4; ++j) kreg[j] = *reinterpret_cast<const short8*>(kgp + j * 8);
            #pragma unroll
            for (int j = 0; j < 4; ++j) vreg[j] = *reinterpret_cast<const short8*>(vgp + j * 8);
        }

        for (int kt = 0; kt < nkt; ++kt) {
            const int kv0 = kt * 64;
            __syncthreads();
            #pragma unroll
            for (int j = 0; j < 4; ++j)
                *reinterpret_cast<short8*>(&Ks[(ksr << 7) + (((((t & 3) << 2) + j) ^ (ksr & 7)) << 3)]) = kreg[j];
            #pragma unroll
            for (int j = 0; j < 4; ++j)
                *reinterpret_cast<short8*>(&Vs[(vsr << 6) + (((((t >> 7) << 2) + j) ^ (vsr & 7)) << 3)]) = vreg[j];
            __syncthreads();
            if (kt + 1 < nkt) {
                const ushort_t* kgp = Kh + (long)(kv0 + 64) * 128 + t * 32;
                const ushort_t* vgp = Vth + (long)vsr * S + kv0 + 64 + vsc;
                #pragma unroll
                for (int j = 0; j < 4; ++j) kreg[j] = *reinterpret_cast<const short8*>(kgp + j * 8);
                #pragma unroll
                for (int j = 0; j < 4; ++j) vreg[j] = *reinterpret_cast<const short8*>(vgp + j * 8);
            }

            f32x4 sacc[4] = {};
            #pragma unroll
            for (int kk = 0; kk < 4; ++kk) {
                #pragma unroll
                for (int n = 0; n < 4; ++n) {
                    short8 kf = *reinterpret_cast<const short8*>(
                        &Ks[((n * 16 + lr) << 7) + ((((kk << 2) + lg) ^ (lr & 7)) << 3)]);
                    sacc[n] = __builtin_amdgcn_mfma_f32_16x16x32_bf16(qf[kk], kf, sacc[n], 0, 0, 0);
                }
            }
            // Q was pre-scaled by scale*log2e in the GEMM epilogue -> softmax in base 2, no mults
            float sv[4][4];
            const int myq = qb0 + wid * 16 + lg * 4;
            #pragma unroll
            for (int n = 0; n < 4; ++n) {
                int kcol = kv0 + n * 16 + lr;
                #pragma unroll
                for (int r = 0; r < 4; ++r)
                    sv[n][r] = (kcol > myq + r) ? -1e9f : sacc[n][r];
            }
            float alpha[4];
            #pragma unroll
            for (int r = 0; r < 4; ++r) {
                float mx = fmaxf(fmaxf(sv[0][r], sv[1][r]), fmaxf(sv[2][r], sv[3][r]));
                #pragma unroll
                for (int off = 1; off < 16; off <<= 1)
                    mx = fmaxf(mx, __shfl_xor(mx, off));
                float mnew = fmaxf(mrow[r], mx);
                alpha[r] = exp2f(mrow[r] - mnew);
                float ts = 0.f;
                #pragma unroll
                for (int n = 0; n < 4; ++n) {
                    float p = exp2f(sv[n][r] - mnew);
                    sv[n][r] = p;
                    ts += p;
                }
                #pragma unroll
                for (int off = 1; off < 16; off <<= 1)
                    ts += __shfl_xor(ts, off);
                lsum[r] = lsum[r] * alpha[r] + ts;
                mrow[r] = mnew;
            }
            #pragma unroll
            for (int f = 0; f < 8; ++f)
                #pragma unroll
                for (int r = 0; r < 4; ++r)
                    oacc[f][r] *= alpha[r];
            #pragma unroll
            for (int n = 0; n < 4; ++n)
                #pragma unroll
                for (int r = 0; r < 4; ++r)
                    Pl[wid][lg * 4 + r][n * 16 + lr] = f2bf(sv[n][r]);
            __asm volatile("" ::: "memory");
            short8 pf[2];
            #pragma unroll
            for (int ks = 0; ks < 2; ++ks)
                pf[ks] = *reinterpret_cast<const short8*>(&Pl[wid][lr][ks * 32 + lg * 8]);
            #pragma unroll
            for (int ks = 0; ks < 2; ++ks) {
                #pragma unroll
                for (int f = 0; f < 8; ++f) {
                    short8 vf = *reinterpret_cast<const short8*>(
                        &Vs[((f * 16 + lr) << 6) + ((((ks << 2) + lg) ^ (lr & 7)) << 3)]);
                    oacc[f] = __builtin_amdgcn_mfma_f32_16x16x32_bf16(pf[ks], vf, oacc[f], 0, 0, 0);
                }
            }
        }
        float inv[4];
        #pragma unroll
        for (int r = 0; r < 4; ++r) inv[r] = 1.f / lsum[r];
        ushort_t* Oh = O + (long)b * S * 2048 + h * 128;
        #pragma unroll
        for (int f = 0; f < 8; ++f) {
            #pragma unroll
            for (int r = 0; r < 4; ++r) {
                int row = qb0 + wid * 16 + lg * 4 + r;
                int col = f * 16 + lr;
                Oh[(long)row * 2048 + col] = f2bf(oacc[f][r] * inv[r]);
            }
        }
    }
}

extern "C" void kernel_launch(void* const* d_in, const int* in_sizes, int n_in,
                              void* d_out, int out_size, void* d_ws, size_t ws_size,
                              hipStream_t stream) {
    const float* x  = (const float*)d_in[0];
    const float* fc = (const float*)d_in[1];
    const float* fs = (const float*)d_in[2];
    const float* wq = (const float*)d_in[3];
    const float* wk = (const float*)d_in[4];
    const float* wv = (const float*)d_in[5];
    const float* wo = (const float*)d_in[6];
    float* out = (float*)d_out;

    const int B = 2, S = 2048, D = 2048, H = 16;
    const int M = B * S;            // 4096
    const size_t MD = (size_t)M * D;
    const size_t DD = (size_t)D * D;

    char* ws = (char*)d_ws;
    ushort_t* xbf = (ushort_t*)ws;                  // A input; attnb overlay after GEMM
    ushort_t* wqb = (ushort_t*)(ws + MD * 2);       // wq|wk|wv|wo bf16 contiguous
    ushort_t* wob = wqb + 3 * DD;
    ushort_t* qp  = wqb + 4 * DD;                   // Q packed [bh,s,128] (pre-scaled)
    ushort_t* kp  = qp + MD;                        // K packed
    ushort_t* vtg = kp + MD;                        // V transposed [bh,128,s]
    float2* fcs   = (float2*)(vtg + MD);            // packed (cos,sin) table, 1MB
    ushort_t* attnb = xbf;                          // overlay: x dead after QKV GEMM

    // 1) fused convert + rope table
    const int npair4 = S * 64 / 4;   // 32768
    cvt_all<<<2048, 256, 0, stream>>>(x, wq, wk, wv, wo, fc, fs, xbf, fcs,
                                      (int)(MD / 8), (int)(DD / 8), npair4);

    // 2) fused QKV projection (128x256 tile, 768 blocks = 3 exact generations)
    dim3 gq(6144 / 256, M / 128);
    gemm256_qkv<<<gq, 512, 98304, stream>>>(xbf, wqb, qp, vtg, fcs, M, 3 * D, D);

    // 3) causal flash attention
    dim3 ga(S / 128, B * H);
    attn_kernel<<<ga, 256, 0, stream>>>(qp, kp, vtg, attnb, S, H);

    // 4) output projection (fp32 out)
    dim3 gg(D / 128, M / 128);
    gemm_nt_f32<<<gg, 256, 0, stream>>>(attnb, wob, out, M, D, D);
}

// Round 12
// 299.325 us; speedup vs baseline: 1.0344x; 1.0344x over previous
//
#include <hip/hip_runtime.h>
#include <hip/hip_bf16.h>
#include <math.h>

typedef __attribute__((ext_vector_type(8))) short short8;
typedef __attribute__((ext_vector_type(4))) short short4v;
typedef __attribute__((ext_vector_type(4))) float f32x4;
typedef unsigned short ushort_t;

// scale(1/sqrt(128)) * log2(e): folded into Q so attn softmax uses exp2 with no mults
#define QK_LOG2E_SCALE 0.1275274059009601f

__device__ __forceinline__ ushort_t f2bf(float f) {
    union { float f; unsigned u; } v; v.f = f;
    unsigned r = v.u + 0x7FFF + ((v.u >> 16) & 1);
    return (ushort_t)(r >> 16);
}

// ---- fused convert: x|wq|wk|wv|wo -> bf16, plus packed float2 (cos,sin) table ----
__global__ void cvt_all(const float* __restrict__ x,
                        const float* __restrict__ w0, const float* __restrict__ w1,
                        const float* __restrict__ w2, const float* __restrict__ w3,
                        const float* __restrict__ fc, const float* __restrict__ fs,
                        ushort_t* __restrict__ dst, float2* __restrict__ fcs,
                        int md8, int dd8, int npair4) {
    int i = blockIdx.x * blockDim.x + threadIdx.x;
    int stride = gridDim.x * blockDim.x;
    const int total0 = md8 + 4 * dd8;
    const int total = total0 + npair4;
    for (; i < total; i += stride) {
        if (i < total0) {
            const float* src;
            long off;
            if (i < md8) { src = x; off = i; }
            else {
                int j = i - md8;
                int which = j / dd8;
                off = j - (long)which * dd8;
                src = (which == 0) ? w0 : (which == 1) ? w1 : (which == 2) ? w2 : w3;
            }
            const float4* s = reinterpret_cast<const float4*>(src) + off * 2;
            float4 a = s[0], b = s[1];
            short8 o;
            o[0] = (short)f2bf(a.x); o[1] = (short)f2bf(a.y);
            o[2] = (short)f2bf(a.z); o[3] = (short)f2bf(a.w);
            o[4] = (short)f2bf(b.x); o[5] = (short)f2bf(b.y);
            o[6] = (short)f2bf(b.z); o[7] = (short)f2bf(b.w);
            reinterpret_cast<short8*>(dst)[i] = o;
        } else {
            int j = i - total0;
            float4 c4 = reinterpret_cast<const float4*>(fc)[j];
            float4 s4 = reinterpret_cast<const float4*>(fs)[j];
            float2* o = fcs + (long)j * 4;
            o[0] = make_float2(c4.x, s4.x);
            o[1] = make_float2(c4.y, s4.y);
            o[2] = make_float2(c4.z, s4.z);
            o[3] = make_float2(c4.w, s4.w);
        }
    }
}

// ============ 128x256 2-phase-per-K-tile GEMM (QKV): BK=64, 8 waves, counted vmcnt ============
// 768 blocks = exactly 3 generations at 1 block/CU (zero idle CUs). ~105us measured (r11).
__global__ __launch_bounds__(512, 2) void gemm256_qkv(const ushort_t* __restrict__ A,
                                                      const ushort_t* __restrict__ Bw,
                                                      ushort_t* __restrict__ Cout,
                                                      ushort_t* __restrict__ Vt,
                                                      const float2* __restrict__ fcs,
                                                      int M, int N, int K) {
    extern __shared__ __align__(16) ushort_t lds[];
    ushort_t* As = lds;              // 16384 elems (32KB)
    ushort_t* Bs = lds + 16384;      // 32768 elems (64KB)
    const int t = threadIdx.x;
    const int wid = t >> 6, lane = t & 63;
    const int wr = wid >> 2, wc = wid & 3;     // 2 row-waves x 4 col-waves
    const int lr = lane & 15, lg = lane >> 4;

    const int ntc = N >> 8;                     // 24 col-tiles (BN=256)
    const int nwg = (M >> 7) * ntc;             // 32*24 = 768
    const int bid = blockIdx.y * gridDim.x + blockIdx.x;
    const int cpx = nwg >> 3;
    const int swz = (bid & 7) * cpx + (bid >> 3);
    const int m0 = (swz / ntc) * 128, n0 = (swz % ntc) * 256;

    f32x4 acc[4][4] = {};

    const int r0 = t >> 3;
    const int c0 = (t & 7) ^ (r0 & 7);
    const ushort_t* gA = A + (long)(m0 + r0) * K + c0 * 8;
    const ushort_t* gB = Bw + (long)(n0 + r0) * K + c0 * 8;

    int aoffE[2];
    aoffE[0] = lr * 64 + (((0 + lg) ^ (lr & 7)) << 3);
    aoffE[1] = lr * 64 + (((4 + lg) ^ (lr & 7)) << 3);

    const int nt = K >> 6;   // 32 (even)

#define STAGE_A(X) do { const int p_ = (X) & 1;                                                \
    __builtin_amdgcn_global_load_lds((const __attribute__((address_space(1))) unsigned int*)   \
        (gA + (X) * 64),                                                                       \
        (__attribute__((address_space(3))) unsigned int*)(As + p_ * 8192 + t * 8), 16, 0, 0);  \
    __builtin_amdgcn_global_load_lds((const __attribute__((address_space(1))) unsigned int*)   \
        (gA + (long)64 * K + (X) * 64),                                                        \
        (__attribute__((address_space(3))) unsigned int*)(As + p_ * 8192 + 4096 + t * 8), 16, 0, 0); } while (0)

#define STAGE_B(X) do { const int p_ = (X) & 1;                                                \
    _Pragma("unroll")                                                                          \
    for (int j_ = 0; j_ < 4; ++j_)                                                             \
        __builtin_amdgcn_global_load_lds((const __attribute__((address_space(1))) unsigned int*) \
            (gB + (long)(j_ * 64) * K + (X) * 64),                                             \
            (__attribute__((address_space(3))) unsigned int*)(Bs + p_ * 16384 + j_ * 4096 + t * 8), 16, 0, 0); } while (0)

#define MIDSYNC() do {                                             \
    asm volatile("" ::: "memory");                                 \
    __builtin_amdgcn_s_barrier();                                  \
    asm volatile("s_waitcnt lgkmcnt(0)" ::: "memory");             \
    __builtin_amdgcn_sched_barrier(0); } while (0)

#define ENDBAR() do {                                              \
    asm volatile("" ::: "memory");                                 \
    __builtin_amdgcn_s_barrier(); } while (0)

#define MFMA_Q(BCOL, BR) do {                                      \
    __builtin_amdgcn_s_setprio(1);                                 \
    _Pragma("unroll")                                              \
    for (int ks = 0; ks < 2; ++ks)                                 \
        _Pragma("unroll")                                          \
        for (int m = 0; m < 4; ++m)                                \
            _Pragma("unroll")                                      \
            for (int n = 0; n < 2; ++n)                            \
                acc[m][(BCOL) + n] =                               \
                    __builtin_amdgcn_mfma_f32_16x16x32_bf16(ar[m][ks], (BR)[n][ks], acc[m][(BCOL) + n], 0, 0, 0); \
    __builtin_amdgcn_s_setprio(0); } while (0)

#define KTILE(U, BUF) do {                                                                     \
    const int Asb = (BUF) * 8192 + wr * 4096;                                                  \
    const int Bcb = (BUF) * 16384 + wc * 4096;                                                 \
    _Pragma("unroll")                                                                          \
    for (int m = 0; m < 4; ++m)                                                                \
        _Pragma("unroll")                                                                      \
        for (int ks = 0; ks < 2; ++ks)                                                         \
            ar[m][ks] = *reinterpret_cast<const short8*>(&As[Asb + m * 1024 + aoffE[ks]]);     \
    _Pragma("unroll")                                                                          \
    for (int n = 0; n < 2; ++n)                                                                \
        _Pragma("unroll")                                                                      \
        for (int ks = 0; ks < 2; ++ks)                                                         \
            br0[n][ks] = *reinterpret_cast<const short8*>(&Bs[Bcb + n * 1024 + aoffE[ks]]);    \
    MIDSYNC();                                                                                 \
    MFMA_Q(0, br0);                                                                            \
    ENDBAR();                                                                                  \
    _Pragma("unroll")                                                                          \
    for (int n = 0; n < 2; ++n)                                                                \
        _Pragma("unroll")                                                                      \
        for (int ks = 0; ks < 2; ++ks)                                                         \
            br1[n][ks] = *reinterpret_cast<const short8*>(&Bs[Bcb + 2048 + n * 1024 + aoffE[ks]]); \
    if ((U) + 2 < nt) STAGE_A((U) + 2);                                                        \
    MIDSYNC();                                                                                 \
    MFMA_Q(2, br1);                                                                            \
    if ((U) + 2 < nt) STAGE_B((U) + 2);                                                        \
    asm volatile("" ::: "memory");                                                             \
    if ((U) < nt - 2) {                                                                        \
        asm volatile("s_waitcnt vmcnt(6)" ::: "memory");                                       \
    } else if ((U) == nt - 2) {                                                                \
        asm volatile("s_waitcnt vmcnt(0)" ::: "memory");                                       \
    }                                                                                          \
    __builtin_amdgcn_s_barrier(); } while (0)

    STAGE_A(0); STAGE_B(0); STAGE_A(1); STAGE_B(1);
    asm volatile("s_waitcnt vmcnt(6)" ::: "memory");
    __builtin_amdgcn_s_barrier();

    short8 ar[4][2], br0[2][2], br1[2][2];

    for (int U = 0; U < nt; U += 2) {
        KTILE(U, 0);
        KTILE(U + 1, 1);
    }
#undef KTILE
#undef MFMA_Q
#undef ENDBAR
#undef MIDSYNC
#undef STAGE_A
#undef STAGE_B

    // ---- fused epilogue: rope(Q*SC)/rope(K) head-packed; V transposed ----
    const int S = 2048;
    #pragma unroll
    for (int m = 0; m < 4; ++m) {
        #pragma unroll
        for (int n = 0; n < 4; ++n) {
            const int col = n0 + wc * 64 + n * 16 + lr;
            const int which = col >> 11;          // block-uniform (2048 % 256 == 0)
            const int h = (col >> 7) & 15;
            const int d = col & 127;
            const int rowb = m0 + wr * 64 + m * 16 + lg * 4;
            const int bb = rowb >> 11;
            const int sb = rowb & 2047;
            if (which == 2) {
                short4v o;
                #pragma unroll
                for (int r = 0; r < 4; ++r) o[r] = (short)f2bf(acc[m][n][r]);
                *reinterpret_cast<short4v*>(Vt + ((long)(bb * 16 + h) * 128 + d) * S + sb) = o;
            } else {
                const int i0 = d >> 1;
                const float qs = (which == 0) ? QK_LOG2E_SCALE : 1.0f;
                #pragma unroll
                for (int r = 0; r < 4; ++r) {
                    const int s = sb + r;
                    float v = acc[m][n][r];
                    float p = __shfl_xor(v, 1);
                    float2 cs = fcs[(long)s * 64 + i0];
                    float o = (lr & 1) ? (p * cs.y + v * cs.x) : (v * cs.x - p * cs.y);
                    Cout[(long)which * M * 2048 + (((long)(bb * 16 + h)) * 2048 + s) * 128 + d] = f2bf(o * qs);
                }
            }
        }
    }
}

// ---------------- GEMM NT 128x128 (proven 2-phase dbuf) — used for wo ----------------
__global__ __launch_bounds__(256) void gemm_nt_f32(const ushort_t* __restrict__ A,
                                                   const ushort_t* __restrict__ Bw,
                                                   float* __restrict__ Cout,
                                                   int M, int N, int K) {
    __shared__ __align__(16) ushort_t As[2 * 128 * 32];
    __shared__ __align__(16) ushort_t Bs[2 * 128 * 32];
    const int t = threadIdx.x;
    const int wid = t >> 6, lane = t & 63;
    const int wm = wid >> 1, wn = wid & 1;
    const int lr = lane & 15, lg = lane >> 4;

    const int ntc = N >> 7;
    const int nwg = (M >> 7) * ntc;
    const int bid = blockIdx.y * gridDim.x + blockIdx.x;
    const int cpx = nwg >> 3;
    const int swz = (bid & 7) * cpx + (bid >> 3);
    const int m0 = (swz / ntc) * 128, n0 = (swz % ntc) * 128;

    f32x4 acc[4][4] = {};

    const int sh0 = wid * 1024 + lane * 8;
    const int sh1 = sh0 + 512;
    const int r0 = sh0 >> 5, c0 = sh0 & 31;
    const int r1 = sh1 >> 5, c1 = sh1 & 31;

    const ushort_t* gA0 = A + (long)(m0 + r0) * K + c0;
    const ushort_t* gA1 = A + (long)(m0 + r1) * K + c1;
    const ushort_t* gB0 = Bw + (long)(n0 + r0) * K + c0;
    const ushort_t* gB1 = Bw + (long)(n0 + r1) * K + c1;

    auto stage = [&](int k0, int nb) {
        ushort_t* as = As + nb * 4096;
        ushort_t* bs = Bs + nb * 4096;
        __builtin_amdgcn_global_load_lds((const __attribute__((address_space(1))) unsigned int*)(gA0 + k0),
                                         (__attribute__((address_space(3))) unsigned int*)(as + sh0), 16, 0, 0);
        __builtin_amdgcn_global_load_lds((const __attribute__((address_space(1))) unsigned int*)(gA1 + k0),
                                         (__attribute__((address_space(3))) unsigned int*)(as + sh1), 16, 0, 0);
        __builtin_amdgcn_global_load_lds((const __attribute__((address_space(1))) unsigned int*)(gB0 + k0),
                                         (__attribute__((address_space(3))) unsigned int*)(bs + sh0), 16, 0, 0);
        __builtin_amdgcn_global_load_lds((const __attribute__((address_space(1))) unsigned int*)(gB1 + k0),
                                         (__attribute__((address_space(3))) unsigned int*)(bs + sh1), 16, 0, 0);
    };

    const int nt = K >> 5;
    stage(0, 0);
    __syncthreads();
    int cur = 0;

    for (int ti = 0; ti < nt; ++ti) {
        if (ti + 1 < nt) stage((ti + 1) << 5, cur ^ 1);
        const ushort_t* as = As + cur * 4096;
        const ushort_t* bs = Bs + cur * 4096;
        short8 af[4], bfr[4];
        #pragma unroll
        for (int m = 0; m < 4; ++m)
            af[m] = *reinterpret_cast<const short8*>(&as[(wm * 64 + m * 16 + lr) * 32 + lg * 8]);
        #pragma unroll
        for (int n = 0; n < 4; ++n)
            bfr[n] = *reinterpret_cast<const short8*>(&bs[(wn * 64 + n * 16 + lr) * 32 + lg * 8]);
        #pragma unroll
        for (int m = 0; m < 4; ++m)
            #pragma unroll
            for (int n = 0; n < 4; ++n)
                acc[m][n] = __builtin_amdgcn_mfma_f32_16x16x32_bf16(af[m], bfr[n], acc[m][n], 0, 0, 0);
        __syncthreads();
        cur ^= 1;
    }

    #pragma unroll
    for (int m = 0; m < 4; ++m) {
        #pragma unroll
        for (int n = 0; n < 4; ++n) {
            const int col = n0 + wn * 64 + n * 16 + lr;
            #pragma unroll
            for (int r = 0; r < 4; ++r) {
                const int row = m0 + wm * 64 + m * 16 + lg * 4 + r;
                Cout[(long)row * N + col] = acc[m][n][r];
            }
        }
    }
}

// ---------------- causal flash attention (round-10 structure; hw exp2, Pl pad 72) ----------------
__global__ __launch_bounds__(256, 3) void attn_kernel(const ushort_t* __restrict__ Qp,
                                                      const ushort_t* __restrict__ Kp,
                                                      const ushort_t* __restrict__ Vtg,
                                                      ushort_t* __restrict__ O,
                                                      int S, int H) {
    __shared__ __align__(16) ushort_t Ks[64 * 128];   // linear, XOR-swizzled 16B slots
    __shared__ __align__(16) ushort_t Vs[128 * 64];   // linear, XOR-swizzled 16B slots
    __shared__ __align__(16) ushort_t Pl[4][16][72];
    const int t = threadIdx.x, wid = t >> 6, lane = t & 63;
    const int lr = lane & 15, lg = lane >> 4;
    const int bh = blockIdx.y;
    const int b = bh / H, h = bh % H;
    const ushort_t* Qh = Qp + (long)bh * S * 128;
    const ushort_t* Kh = Kp + (long)bh * S * 128;
    const ushort_t* Vth = Vtg + (long)bh * 128 * S;
    const int nq = S / 64;

    const int ksr = t >> 2;
    const int vsr = t & 127;
    const int vsc = (t >> 7) * 32;

    for (int qsel = 0; qsel < 2; ++qsel) {
        const int qt = qsel ? (nq - 1 - blockIdx.x) : blockIdx.x;
        const int qb0 = qt * 64;

        const int qrow = qb0 + wid * 16 + lr;
        short8 qf[4];
        #pragma unroll
        for (int kk = 0; kk < 4; ++kk)
            qf[kk] = *reinterpret_cast<const short8*>(Qh + (long)qrow * 128 + kk * 32 + lg * 8);

        f32x4 oacc[8] = {};
        float mrow[4], lsum[4];
        #pragma unroll
        for (int r = 0; r < 4; ++r) { mrow[r] = -INFINITY; lsum[r] = 0.f; }

        const int nkt = qt + 1;

        short8 kreg[4], vreg[4];
        {
            const ushort_t* kgp = Kh + t * 32;
            const ushort_t* vgp = Vth + (long)vsr * S + vsc;
            #pragma unroll
            for (int j = 0; j < 4; ++j) kreg[j] = *reinterpret_cast<const short8*>(kgp + j * 8);
            #pragma unroll
            for (int j = 0; j < 4; ++j) vreg[j] = *reinterpret_cast<const short8*>(vgp + j * 8);
        }

        for (int kt = 0; kt < nkt; ++kt) {
            const int kv0 = kt * 64;
            __syncthreads();
            #pragma unroll
            for (int j = 0; j < 4; ++j)
                *reinterpret_cast<short8*>(&Ks[(ksr << 7) + (((((t & 3) << 2) + j) ^ (ksr & 7)) << 3)]) = kreg[j];
            #pragma unroll
            for (int j = 0; j < 4; ++j)
                *reinterpret_cast<short8*>(&Vs[(vsr << 6) + (((((t >> 7) << 2) + j) ^ (vsr & 7)) << 3)]) = vreg[j];
            __syncthreads();
            if (kt + 1 < nkt) {
                const ushort_t* kgp = Kh + (long)(kv0 + 64) * 128 + t * 32;
                const ushort_t* vgp = Vth + (long)vsr * S + kv0 + 64 + vsc;
                #pragma unroll
                for (int j = 0; j < 4; ++j) kreg[j] = *reinterpret_cast<const short8*>(kgp + j * 8);
                #pragma unroll
                for (int j = 0; j < 4; ++j) vreg[j] = *reinterpret_cast<const short8*>(vgp + j * 8);
            }

            f32x4 sacc[4] = {};
            #pragma unroll
            for (int kk = 0; kk < 4; ++kk) {
                #pragma unroll
                for (int n = 0; n < 4; ++n) {
                    short8 kf = *reinterpret_cast<const short8*>(
                        &Ks[((n * 16 + lr) << 7) + ((((kk << 2) + lg) ^ (lr & 7)) << 3)]);
                    sacc[n] = __builtin_amdgcn_mfma_f32_16x16x32_bf16(qf[kk], kf, sacc[n], 0, 0, 0);
                }
            }
            // Q pre-scaled by scale*log2e -> base-2 softmax via raw v_exp_f32
            float sv[4][4];
            const int myq = qb0 + wid * 16 + lg * 4;
            #pragma unroll
            for (int n = 0; n < 4; ++n) {
                int kcol = kv0 + n * 16 + lr;
                #pragma unroll
                for (int r = 0; r < 4; ++r)
                    sv[n][r] = (kcol > myq + r) ? -1e9f : sacc[n][r];
            }
            float alpha[4];
            #pragma unroll
            for (int r = 0; r < 4; ++r) {
                float mx = fmaxf(fmaxf(sv[0][r], sv[1][r]), fmaxf(sv[2][r], sv[3][r]));
                #pragma unroll
                for (int off = 1; off < 16; off <<= 1)
                    mx = fmaxf(mx, __shfl_xor(mx, off));
                float mnew = fmaxf(mrow[r], mx);
                alpha[r] = __builtin_amdgcn_exp2f(mrow[r] - mnew);
                float ts = 0.f;
                #pragma unroll
                for (int n = 0; n < 4; ++n) {
                    float p = __builtin_amdgcn_exp2f(sv[n][r] - mnew);
                    sv[n][r] = p;
                    ts += p;
                }
                #pragma unroll
                for (int off = 1; off < 16; off <<= 1)
                    ts += __shfl_xor(ts, off);
                lsum[r] = lsum[r] * alpha[r] + ts;
                mrow[r] = mnew;
            }
            #pragma unroll
            for (int f = 0; f < 8; ++f)
                #pragma unroll
                for (int r = 0; r < 4; ++r)
                    oacc[f][r] *= alpha[r];
            #pragma unroll
            for (int n = 0; n < 4; ++n)
                #pragma unroll
                for (int r = 0; r < 4; ++r)
                    Pl[wid][lg * 4 + r][n * 16 + lr] = f2bf(sv[n][r]);
            __asm volatile("" ::: "memory");
            short8 pf[2];
            #pragma unroll
            for (int ks = 0; ks < 2; ++ks)
                pf[ks] = *reinterpret_cast<const short8*>(&Pl[wid][lr][ks * 32 + lg * 8]);
            #pragma unroll
            for (int ks = 0; ks < 2; ++ks) {
                #pragma unroll
                for (int f = 0; f < 8; ++f) {
                    short8 vf = *reinterpret_cast<const short8*>(
                        &Vs[((f * 16 + lr) << 6) + ((((ks << 2) + lg) ^ (lr & 7)) << 3)]);
                    oacc[f] = __builtin_amdgcn_mfma_f32_16x16x32_bf16(pf[ks], vf, oacc[f], 0, 0, 0);
                }
            }
        }
        float inv[4];
        #pragma unroll
        for (int r = 0; r < 4; ++r) inv[r] = 1.f / lsum[r];
        ushort_t* Oh = O + (long)b * S * 2048 + h * 128;
        #pragma unroll
        for (int f = 0; f < 8; ++f) {
            #pragma unroll
            for (int r = 0; r < 4; ++r) {
                int row = qb0 + wid * 16 + lg * 4 + r;
                int col = f * 16 + lr;
                Oh[(long)row * 2048 + col] = f2bf(oacc[f][r] * inv[r]);
            }
        }
    }
}

extern "C" void kernel_launch(void* const* d_in, const int* in_sizes, int n_in,
                              void* d_out, int out_size, void* d_ws, size_t ws_size,
                              hipStream_t stream) {
    const float* x  = (const float*)d_in[0];
    const float* fc = (const float*)d_in[1];
    const float* fs = (const float*)d_in[2];
    const float* wq = (const float*)d_in[3];
    const float* wk = (const float*)d_in[4];
    const float* wv = (const float*)d_in[5];
    const float* wo = (const float*)d_in[6];
    float* out = (float*)d_out;

    const int B = 2, S = 2048, D = 2048, H = 16;
    const int M = B * S;            // 4096
    const size_t MD = (size_t)M * D;
    const size_t DD = (size_t)D * D;

    char* ws = (char*)d_ws;
    ushort_t* xbf = (ushort_t*)ws;                  // A input; attnb overlay after GEMM
    ushort_t* wqb = (ushort_t*)(ws + MD * 2);       // wq|wk|wv|wo bf16 contiguous
    ushort_t* wob = wqb + 3 * DD;
    ushort_t* qp  = wqb + 4 * DD;                   // Q packed [bh,s,128] (pre-scaled)
    ushort_t* kp  = qp + MD;                        // K packed
    ushort_t* vtg = kp + MD;                        // V transposed [bh,128,s]
    float2* fcs   = (float2*)(vtg + MD);            // packed (cos,sin) table, 1MB
    ushort_t* attnb = xbf;                          // overlay: x dead after QKV GEMM

    // 1) fused convert + rope table
    const int npair4 = S * 64 / 4;   // 32768
    cvt_all<<<2048, 256, 0, stream>>>(x, wq, wk, wv, wo, fc, fs, xbf, fcs,
                                      (int)(MD / 8), (int)(DD / 8), npair4);

    // 2) fused QKV projection (128x256 tile, 768 blocks = 3 exact generations)
    dim3 gq(6144 / 256, M / 128);
    gemm256_qkv<<<gq, 512, 98304, stream>>>(xbf, wqb, qp, vtg, fcs, M, 3 * D, D);

    // 3) causal flash attention
    dim3 ga(S / 128, B * H);
    attn_kernel<<<ga, 256, 0, stream>>>(qp, kp, vtg, attnb, S, H);

    // 4) output projection (fp32 out)
    dim3 gg(D / 128, M / 128);
    gemm_nt_f32<<<gg, 256, 0, stream>>>(attnb, wob, out, M, D, D);
}

// Round 13
// 291.073 us; speedup vs baseline: 1.0638x; 1.0283x over previous
//
#include <hip/hip_runtime.h>
#include <hip/hip_bf16.h>
#include <math.h>

typedef __attribute__((ext_vector_type(8))) short short8;
typedef __attribute__((ext_vector_type(4))) short short4v;
typedef __attribute__((ext_vector_type(4))) float f32x4;
typedef unsigned short ushort_t;

// scale(1/sqrt(128)) * log2(e): folded into Q so attn softmax uses exp2 with no mults
#define QK_LOG2E_SCALE 0.1275274059009601f

__device__ __forceinline__ ushort_t f2bf(float f) {
    union { float f; unsigned u; } v; v.f = f;
    unsigned r = v.u + 0x7FFF + ((v.u >> 16) & 1);
    return (ushort_t)(r >> 16);
}

// ---- fused convert: x|wq|wk|wv|wo -> bf16, plus packed float2 (cos,sin) table ----
__global__ void cvt_all(const float* __restrict__ x,
                        const float* __restrict__ w0, const float* __restrict__ w1,
                        const float* __restrict__ w2, const float* __restrict__ w3,
                        const float* __restrict__ fc, const float* __restrict__ fs,
                        ushort_t* __restrict__ dst, float2* __restrict__ fcs,
                        int md8, int dd8, int npair4) {
    int i = blockIdx.x * blockDim.x + threadIdx.x;
    int stride = gridDim.x * blockDim.x;
    const int total0 = md8 + 4 * dd8;
    const int total = total0 + npair4;
    for (; i < total; i += stride) {
        if (i < total0) {
            const float* src;
            long off;
            if (i < md8) { src = x; off = i; }
            else {
                int j = i - md8;
                int which = j / dd8;
                off = j - (long)which * dd8;
                src = (which == 0) ? w0 : (which == 1) ? w1 : (which == 2) ? w2 : w3;
            }
            const float4* s = reinterpret_cast<const float4*>(src) + off * 2;
            float4 a = s[0], b = s[1];
            short8 o;
            o[0] = (short)f2bf(a.x); o[1] = (short)f2bf(a.y);
            o[2] = (short)f2bf(a.z); o[3] = (short)f2bf(a.w);
            o[4] = (short)f2bf(b.x); o[5] = (short)f2bf(b.y);
            o[6] = (short)f2bf(b.z); o[7] = (short)f2bf(b.w);
            reinterpret_cast<short8*>(dst)[i] = o;
        } else {
            int j = i - total0;
            float4 c4 = reinterpret_cast<const float4*>(fc)[j];
            float4 s4 = reinterpret_cast<const float4*>(fs)[j];
            float2* o = fcs + (long)j * 4;
            o[0] = make_float2(c4.x, s4.x);
            o[1] = make_float2(c4.y, s4.y);
            o[2] = make_float2(c4.z, s4.z);
            o[3] = make_float2(c4.w, s4.w);
        }
    }
}

// ============ 128x256 2-phase-per-K-tile GEMM: BK=64, 8 waves, counted vmcnt ============
// EPI=1: fused RoPE/transposed-V QKV epilogue (bf16). EPI=0: plain fp32 [M,N] out (wo).
// For wo: grid 32x8 = 256 blocks = exactly 1 full generation at 1 block/CU.
template<int EPI>
__global__ __launch_bounds__(512, 2) void gemm_wide(const ushort_t* __restrict__ A,
                                                    const ushort_t* __restrict__ Bw,
                                                    void* __restrict__ Cout,
                                                    ushort_t* __restrict__ Vt,
                                                    const float2* __restrict__ fcs,
                                                    int M, int N, int K) {
    extern __shared__ __align__(16) ushort_t lds[];
    ushort_t* As = lds;              // 16384 elems (32KB)
    ushort_t* Bs = lds + 16384;      // 32768 elems (64KB)
    const int t = threadIdx.x;
    const int wid = t >> 6, lane = t & 63;
    const int wr = wid >> 2, wc = wid & 3;     // 2 row-waves x 4 col-waves
    const int lr = lane & 15, lg = lane >> 4;

    const int ntc = N >> 8;
    const int nwg = (M >> 7) * ntc;
    const int bid = blockIdx.y * gridDim.x + blockIdx.x;
    const int cpx = nwg >> 3;
    const int swz = (bid & 7) * cpx + (bid >> 3);
    const int m0 = (swz / ntc) * 128, n0 = (swz % ntc) * 256;

    f32x4 acc[4][4] = {};

    const int r0 = t >> 3;
    const int c0 = (t & 7) ^ (r0 & 7);
    const ushort_t* gA = A + (long)(m0 + r0) * K + c0 * 8;
    const ushort_t* gB = Bw + (long)(n0 + r0) * K + c0 * 8;

    int aoffE[2];
    aoffE[0] = lr * 64 + (((0 + lg) ^ (lr & 7)) << 3);
    aoffE[1] = lr * 64 + (((4 + lg) ^ (lr & 7)) << 3);

    const int nt = K >> 6;   // 32 (even)

#define STAGE_A(X) do { const int p_ = (X) & 1;                                                \
    __builtin_amdgcn_global_load_lds((const __attribute__((address_space(1))) unsigned int*)   \
        (gA + (X) * 64),                                                                       \
        (__attribute__((address_space(3))) unsigned int*)(As + p_ * 8192 + t * 8), 16, 0, 0);  \
    __builtin_amdgcn_global_load_lds((const __attribute__((address_space(1))) unsigned int*)   \
        (gA + (long)64 * K + (X) * 64),                                                        \
        (__attribute__((address_space(3))) unsigned int*)(As + p_ * 8192 + 4096 + t * 8), 16, 0, 0); } while (0)

#define STAGE_B(X) do { const int p_ = (X) & 1;                                                \
    _Pragma("unroll")                                                                          \
    for (int j_ = 0; j_ < 4; ++j_)                                                             \
        __builtin_amdgcn_global_load_lds((const __attribute__((address_space(1))) unsigned int*) \
            (gB + (long)(j_ * 64) * K + (X) * 64),                                             \
            (__attribute__((address_space(3))) unsigned int*)(Bs + p_ * 16384 + j_ * 4096 + t * 8), 16, 0, 0); } while (0)

#define MIDSYNC() do {                                             \
    asm volatile("" ::: "memory");                                 \
    __builtin_amdgcn_s_barrier();                                  \
    asm volatile("s_waitcnt lgkmcnt(0)" ::: "memory");             \
    __builtin_amdgcn_sched_barrier(0); } while (0)

#define ENDBAR() do {                                              \
    asm volatile("" ::: "memory");                                 \
    __builtin_amdgcn_s_barrier(); } while (0)

#define MFMA_Q(BCOL, BR) do {                                      \
    __builtin_amdgcn_s_setprio(1);                                 \
    _Pragma("unroll")                                              \
    for (int ks = 0; ks < 2; ++ks)                                 \
        _Pragma("unroll")                                          \
        for (int m = 0; m < 4; ++m)                                \
            _Pragma("unroll")                                      \
            for (int n = 0; n < 2; ++n)                            \
                acc[m][(BCOL) + n] =                               \
                    __builtin_amdgcn_mfma_f32_16x16x32_bf16(ar[m][ks], (BR)[n][ks], acc[m][(BCOL) + n], 0, 0, 0); \
    __builtin_amdgcn_s_setprio(0); } while (0)

#define KTILE(U, BUF) do {                                                                     \
    const int Asb = (BUF) * 8192 + wr * 4096;                                                  \
    const int Bcb = (BUF) * 16384 + wc * 4096;                                                 \
    _Pragma("unroll")                                                                          \
    for (int m = 0; m < 4; ++m)                                                                \
        _Pragma("unroll")                                                                      \
        for (int ks = 0; ks < 2; ++ks)                                                         \
            ar[m][ks] = *reinterpret_cast<const short8*>(&As[Asb + m * 1024 + aoffE[ks]]);     \
    _Pragma("unroll")                                                                          \
    for (int n = 0; n < 2; ++n)                                                                \
        _Pragma("unroll")                                                                      \
        for (int ks = 0; ks < 2; ++ks)                                                         \
            br0[n][ks] = *reinterpret_cast<const short8*>(&Bs[Bcb + n * 1024 + aoffE[ks]]);    \
    MIDSYNC();                                                                                 \
    MFMA_Q(0, br0);                                                                            \
    ENDBAR();                                                                                  \
    _Pragma("unroll")                                                                          \
    for (int n = 0; n < 2; ++n)                                                                \
        _Pragma("unroll")                                                                      \
        for (int ks = 0; ks < 2; ++ks)                                                         \
            br1[n][ks] = *reinterpret_cast<const short8*>(&Bs[Bcb + 2048 + n * 1024 + aoffE[ks]]); \
    if ((U) + 2 < nt) STAGE_A((U) + 2);                                                        \
    MIDSYNC();                                                                                 \
    MFMA_Q(2, br1);                                                                            \
    if ((U) + 2 < nt) STAGE_B((U) + 2);                                                        \
    asm volatile("" ::: "memory");                                                             \
    if ((U) < nt - 2) {                                                                        \
        asm volatile("s_waitcnt vmcnt(6)" ::: "memory");                                       \
    } else if ((U) == nt - 2) {                                                                \
        asm volatile("s_waitcnt vmcnt(0)" ::: "memory");                                       \
    }                                                                                          \
    __builtin_amdgcn_s_barrier(); } while (0)

    STAGE_A(0); STAGE_B(0); STAGE_A(1); STAGE_B(1);
    asm volatile("s_waitcnt vmcnt(6)" ::: "memory");
    __builtin_amdgcn_s_barrier();

    short8 ar[4][2], br0[2][2], br1[2][2];

    for (int U = 0; U < nt; U += 2) {
        KTILE(U, 0);
        KTILE(U + 1, 1);
    }
#undef KTILE
#undef MFMA_Q
#undef ENDBAR
#undef MIDSYNC
#undef STAGE_A
#undef STAGE_B

    const int S = 2048;
    #pragma unroll
    for (int m = 0; m < 4; ++m) {
        #pragma unroll
        for (int n = 0; n < 4; ++n) {
            const int col = n0 + wc * 64 + n * 16 + lr;
            const int rowb = m0 + wr * 64 + m * 16 + lg * 4;
            if (EPI == 0) {
                #pragma unroll
                for (int r = 0; r < 4; ++r)
                    ((float*)Cout)[(long)(rowb + r) * N + col] = acc[m][n][r];
            } else {
                const int which = col >> 11;          // block-uniform (2048 % 256 == 0)
                const int h = (col >> 7) & 15;
                const int d = col & 127;
                const int bb = rowb >> 11;
                const int sb = rowb & 2047;
                if (which == 2) {
                    short4v o;
                    #pragma unroll
                    for (int r = 0; r < 4; ++r) o[r] = (short)f2bf(acc[m][n][r]);
                    *reinterpret_cast<short4v*>(Vt + ((long)(bb * 16 + h) * 128 + d) * S + sb) = o;
                } else {
                    const int i0 = d >> 1;
                    const float qs = (which == 0) ? QK_LOG2E_SCALE : 1.0f;
                    #pragma unroll
                    for (int r = 0; r < 4; ++r) {
                        const int s = sb + r;
                        float v = acc[m][n][r];
                        float p = __shfl_xor(v, 1);
                        float2 cs = fcs[(long)s * 64 + i0];
                        float o = (lr & 1) ? (p * cs.y + v * cs.x) : (v * cs.x - p * cs.y);
                        ((ushort_t*)Cout)[(long)which * M * 2048 +
                                          (((long)(bb * 16 + h)) * 2048 + s) * 128 + d] = f2bf(o * qs);
                    }
                }
            }
        }
    }
}

// ---------------- causal flash attention (hw exp2; mask only on diagonal tile) ----------------
__global__ __launch_bounds__(256, 3) void attn_kernel(const ushort_t* __restrict__ Qp,
                                                      const ushort_t* __restrict__ Kp,
                                                      const ushort_t* __restrict__ Vtg,
                                                      ushort_t* __restrict__ O,
                                                      int S, int H) {
    __shared__ __align__(16) ushort_t Ks[64 * 128];   // linear, XOR-swizzled 16B slots
    __shared__ __align__(16) ushort_t Vs[128 * 64];   // linear, XOR-swizzled 16B slots
    __shared__ __align__(16) ushort_t Pl[4][16][72];
    const int t = threadIdx.x, wid = t >> 6, lane = t & 63;
    const int lr = lane & 15, lg = lane >> 4;
    const int bh = blockIdx.y;
    const int b = bh / H, h = bh % H;
    const ushort_t* Qh = Qp + (long)bh * S * 128;
    const ushort_t* Kh = Kp + (long)bh * S * 128;
    const ushort_t* Vth = Vtg + (long)bh * 128 * S;
    const int nq = S / 64;

    const int ksr = t >> 2;
    const int vsr = t & 127;
    const int vsc = (t >> 7) * 32;

    for (int qsel = 0; qsel < 2; ++qsel) {
        const int qt = qsel ? (nq - 1 - blockIdx.x) : blockIdx.x;
        const int qb0 = qt * 64;

        const int qrow = qb0 + wid * 16 + lr;
        short8 qf[4];
        #pragma unroll
        for (int kk = 0; kk < 4; ++kk)
            qf[kk] = *reinterpret_cast<const short8*>(Qh + (long)qrow * 128 + kk * 32 + lg * 8);

        f32x4 oacc[8] = {};
        float mrow[4], lsum[4];
        #pragma unroll
        for (int r = 0; r < 4; ++r) { mrow[r] = -INFINITY; lsum[r] = 0.f; }

        const int nkt = qt + 1;

        short8 kreg[4], vreg[4];
        {
            const ushort_t* kgp = Kh + t * 32;
            const ushort_t* vgp = Vth + (long)vsr * S + vsc;
            #pragma unroll
            for (int j = 0; j < 4; ++j) kreg[j] = *reinterpret_cast<const short8*>(kgp + j * 8);
            #pragma unroll
            for (int j = 0; j < 4; ++j) vreg[j] = *reinterpret_cast<const short8*>(vgp + j * 8);
        }

        for (int kt = 0; kt < nkt; ++kt) {
            const int kv0 = kt * 64;
            __syncthreads();
            #pragma unroll
            for (int j = 0; j < 4; ++j)
                *reinterpret_cast<short8*>(&Ks[(ksr << 7) + (((((t & 3) << 2) + j) ^ (ksr & 7)) << 3)]) = kreg[j];
            #pragma unroll
            for (int j = 0; j < 4; ++j)
                *reinterpret_cast<short8*>(&Vs[(vsr << 6) + (((((t >> 7) << 2) + j) ^ (vsr & 7)) << 3)]) = vreg[j];
            __syncthreads();
            if (kt + 1 < nkt) {
                const ushort_t* kgp = Kh + (long)(kv0 + 64) * 128 + t * 32;
                const ushort_t* vgp = Vth + (long)vsr * S + kv0 + 64 + vsc;
                #pragma unroll
                for (int j = 0; j < 4; ++j) kreg[j] = *reinterpret_cast<const short8*>(kgp + j * 8);
                #pragma unroll
                for (int j = 0; j < 4; ++j) vreg[j] = *reinterpret_cast<const short8*>(vgp + j * 8);
            }

            f32x4 sacc[4] = {};
            #pragma unroll
            for (int kk = 0; kk < 4; ++kk) {
                #pragma unroll
                for (int n = 0; n < 4; ++n) {
                    short8 kf = *reinterpret_cast<const short8*>(
                        &Ks[((n * 16 + lr) << 7) + ((((kk << 2) + lg) ^ (lr & 7)) << 3)]);
                    sacc[n] = __builtin_amdgcn_mfma_f32_16x16x32_bf16(qf[kk], kf, sacc[n], 0, 0, 0);
                }
            }
            // Q pre-scaled by scale*log2e -> base-2 softmax via raw v_exp_f32.
            // Mask only triggers on the diagonal tile (kt == qt); wave-uniform branch.
            float sv[4][4];
            if (kt == qt) {
                const int myq = qb0 + wid * 16 + lg * 4;
                #pragma unroll
                for (int n = 0; n < 4; ++n) {
                    int kcol = kv0 + n * 16 + lr;
                    #pragma unroll
                    for (int r = 0; r < 4; ++r)
                        sv[n][r] = (kcol > myq + r) ? -1e9f : sacc[n][r];
                }
            } else {
                #pragma unroll
                for (int n = 0; n < 4; ++n)
                    #pragma unroll
                    for (int r = 0; r < 4; ++r)
                        sv[n][r] = sacc[n][r];
            }
            float alpha[4];
            #pragma unroll
            for (int r = 0; r < 4; ++r) {
                float mx = fmaxf(fmaxf(sv[0][r], sv[1][r]), fmaxf(sv[2][r], sv[3][r]));
                #pragma unroll
                for (int off = 1; off < 16; off <<= 1)
                    mx = fmaxf(mx, __shfl_xor(mx, off));
                float mnew = fmaxf(mrow[r], mx);
                alpha[r] = __builtin_amdgcn_exp2f(mrow[r] - mnew);
                float ts = 0.f;
                #pragma unroll
                for (int n = 0; n < 4; ++n) {
                    float p = __builtin_amdgcn_exp2f(sv[n][r] - mnew);
                    sv[n][r] = p;
                    ts += p;
                }
                #pragma unroll
                for (int off = 1; off < 16; off <<= 1)
                    ts += __shfl_xor(ts, off);
                lsum[r] = lsum[r] * alpha[r] + ts;
                mrow[r] = mnew;
            }
            #pragma unroll
            for (int f = 0; f < 8; ++f)
                #pragma unroll
                for (int r = 0; r < 4; ++r)
                    oacc[f][r] *= alpha[r];
            #pragma unroll
            for (int n = 0; n < 4; ++n)
                #pragma unroll
                for (int r = 0; r < 4; ++r)
                    Pl[wid][lg * 4 + r][n * 16 + lr] = f2bf(sv[n][r]);
            __asm volatile("" ::: "memory");
            short8 pf[2];
            #pragma unroll
            for (int ks = 0; ks < 2; ++ks)
                pf[ks] = *reinterpret_cast<const short8*>(&Pl[wid][lr][ks * 32 + lg * 8]);
            #pragma unroll
            for (int ks = 0; ks < 2; ++ks) {
                #pragma unroll
                for (int f = 0; f < 8; ++f) {
                    short8 vf = *reinterpret_cast<const short8*>(
                        &Vs[((f * 16 + lr) << 6) + ((((ks << 2) + lg) ^ (lr & 7)) << 3)]);
                    oacc[f] = __builtin_amdgcn_mfma_f32_16x16x32_bf16(pf[ks], vf, oacc[f], 0, 0, 0);
                }
            }
        }
        float inv[4];
        #pragma unroll
        for (int r = 0; r < 4; ++r) inv[r] = 1.f / lsum[r];
        ushort_t* Oh = O + (long)b * S * 2048 + h * 128;
        #pragma unroll
        for (int f = 0; f < 8; ++f) {
            #pragma unroll
            for (int r = 0; r < 4; ++r) {
                int row = qb0 + wid * 16 + lg * 4 + r;
                int col = f * 16 + lr;
                Oh[(long)row * 2048 + col] = f2bf(oacc[f][r] * inv[r]);
            }
        }
    }
}

extern "C" void kernel_launch(void* const* d_in, const int* in_sizes, int n_in,
                              void* d_out, int out_size, void* d_ws, size_t ws_size,
                              hipStream_t stream) {
    const float* x  = (const float*)d_in[0];
    const float* fc = (const float*)d_in[1];
    const float* fs = (const float*)d_in[2];
    const float* wq = (const float*)d_in[3];
    const float* wk = (const float*)d_in[4];
    const float* wv = (const float*)d_in[5];
    const float* wo = (const float*)d_in[6];
    float* out = (float*)d_out;

    const int B = 2, S = 2048, D = 2048, H = 16;
    const int M = B * S;            // 4096
    const size_t MD = (size_t)M * D;
    const size_t DD = (size_t)D * D;

    char* ws = (char*)d_ws;
    ushort_t* xbf = (ushort_t*)ws;                  // A input; attnb overlay after GEMM
    ushort_t* wqb = (ushort_t*)(ws + MD * 2);       // wq|wk|wv|wo bf16 contiguous
    ushort_t* wob = wqb + 3 * DD;
    ushort_t* qp  = wqb + 4 * DD;                   // Q packed [bh,s,128] (pre-scaled)
    ushort_t* kp  = qp + MD;                        // K packed
    ushort_t* vtg = kp + MD;                        // V transposed [bh,128,s]
    float2* fcs   = (float2*)(vtg + MD);            // packed (cos,sin) table, 1MB
    ushort_t* attnb = xbf;                          // overlay: x dead after QKV GEMM

    // 1) fused convert + rope table
    const int npair4 = S * 64 / 4;   // 32768
    cvt_all<<<2048, 256, 0, stream>>>(x, wq, wk, wv, wo, fc, fs, xbf, fcs,
                                      (int)(MD / 8), (int)(DD / 8), npair4);

    // 2) fused QKV projection (128x256 tile, 768 blocks = 3 exact generations)
    dim3 gq(6144 / 256, M / 128);
    gemm_wide<1><<<gq, 512, 98304, stream>>>(xbf, wqb, qp, vtg, fcs, M, 3 * D, D);

    // 3) causal flash attention
    dim3 ga(S / 128, B * H);
    attn_kernel<<<ga, 256, 0, stream>>>(qp, kp, vtg, attnb, S, H);

    // 4) output projection (fp32 out): 256 blocks = exactly 1 full generation
    dim3 gg(D / 256, M / 128);
    gemm_wide<0><<<gg, 512, 98304, stream>>>(attnb, wob, out, nullptr, nullptr, M, D, D);
}

// Round 14
// 289.675 us; speedup vs baseline: 1.0689x; 1.0048x over previous
//
#include <hip/hip_runtime.h>
#include <hip/hip_bf16.h>
#include <math.h>

typedef __attribute__((ext_vector_type(8))) short short8;
typedef __attribute__((ext_vector_type(4))) short short4v;
typedef __attribute__((ext_vector_type(4))) float f32x4;
typedef unsigned short ushort_t;

// scale(1/sqrt(128)) * log2(e): folded into Q so attn softmax uses exp2 with no mults
#define QK_LOG2E_SCALE 0.1275274059009601f

__device__ __forceinline__ ushort_t f2bf(float f) {
    union { float f; unsigned u; } v; v.f = f;
    unsigned r = v.u + 0x7FFF + ((v.u >> 16) & 1);
    return (ushort_t)(r >> 16);
}

// ---- fused convert: x|wq|wk|wv|wo -> bf16, plus packed float2 (cos,sin) table ----
__global__ void cvt_all(const float* __restrict__ x,
                        const float* __restrict__ w0, const float* __restrict__ w1,
                        const float* __restrict__ w2, const float* __restrict__ w3,
                        const float* __restrict__ fc, const float* __restrict__ fs,
                        ushort_t* __restrict__ dst, float2* __restrict__ fcs,
                        int md8, int dd8, int npair4) {
    int i = blockIdx.x * blockDim.x + threadIdx.x;
    int stride = gridDim.x * blockDim.x;
    const int total0 = md8 + 4 * dd8;
    const int total = total0 + npair4;
    for (; i < total; i += stride) {
        if (i < total0) {
            const float* src;
            long off;
            if (i < md8) { src = x; off = i; }
            else {
                int j = i - md8;
                int which = j / dd8;
                off = j - (long)which * dd8;
                src = (which == 0) ? w0 : (which == 1) ? w1 : (which == 2) ? w2 : w3;
            }
            const float4* s = reinterpret_cast<const float4*>(src) + off * 2;
            float4 a = s[0], b = s[1];
            short8 o;
            o[0] = (short)f2bf(a.x); o[1] = (short)f2bf(a.y);
            o[2] = (short)f2bf(a.z); o[3] = (short)f2bf(a.w);
            o[4] = (short)f2bf(b.x); o[5] = (short)f2bf(b.y);
            o[6] = (short)f2bf(b.z); o[7] = (short)f2bf(b.w);
            reinterpret_cast<short8*>(dst)[i] = o;
        } else {
            int j = i - total0;
            float4 c4 = reinterpret_cast<const float4*>(fc)[j];
            float4 s4 = reinterpret_cast<const float4*>(fs)[j];
            float2* o = fcs + (long)j * 4;
            o[0] = make_float2(c4.x, s4.x);
            o[1] = make_float2(c4.y, s4.y);
            o[2] = make_float2(c4.z, s4.z);
            o[3] = make_float2(c4.w, s4.w);
        }
    }
}

// ============ 128x256 2-phase-per-K-tile GEMM: BK=64, 8 waves, counted vmcnt ============
// EPI=1: fused RoPE/transposed-V QKV epilogue (bf16). EPI=0: plain fp32 [M,N] out (wo).
template<int EPI>
__global__ __launch_bounds__(512, 2) void gemm_wide(const ushort_t* __restrict__ A,
                                                    const ushort_t* __restrict__ Bw,
                                                    void* __restrict__ Cout,
                                                    ushort_t* __restrict__ Vt,
                                                    const float2* __restrict__ fcs,
                                                    int M, int N, int K) {
    extern __shared__ __align__(16) ushort_t lds[];
    ushort_t* As = lds;              // 16384 elems (32KB)
    ushort_t* Bs = lds + 16384;      // 32768 elems (64KB)
    const int t = threadIdx.x;
    const int wid = t >> 6, lane = t & 63;
    const int wr = wid >> 2, wc = wid & 3;     // 2 row-waves x 4 col-waves
    const int lr = lane & 15, lg = lane >> 4;

    const int ntc = N >> 8;
    const int nwg = (M >> 7) * ntc;
    const int bid = blockIdx.y * gridDim.x + blockIdx.x;
    const int cpx = nwg >> 3;
    const int swz = (bid & 7) * cpx + (bid >> 3);
    const int m0 = (swz / ntc) * 128, n0 = (swz % ntc) * 256;

    f32x4 acc[4][4] = {};

    const int r0 = t >> 3;
    const int c0 = (t & 7) ^ (r0 & 7);
    const ushort_t* gA = A + (long)(m0 + r0) * K + c0 * 8;
    const ushort_t* gB = Bw + (long)(n0 + r0) * K + c0 * 8;

    int aoffE[2];
    aoffE[0] = lr * 64 + (((0 + lg) ^ (lr & 7)) << 3);
    aoffE[1] = lr * 64 + (((4 + lg) ^ (lr & 7)) << 3);

    const int nt = K >> 6;   // 32 (even)

#define STAGE_A(X) do { const int p_ = (X) & 1;                                                \
    __builtin_amdgcn_global_load_lds((const __attribute__((address_space(1))) unsigned int*)   \
        (gA + (X) * 64),                                                                       \
        (__attribute__((address_space(3))) unsigned int*)(As + p_ * 8192 + t * 8), 16, 0, 0);  \
    __builtin_amdgcn_global_load_lds((const __attribute__((address_space(1))) unsigned int*)   \
        (gA + (long)64 * K + (X) * 64),                                                        \
        (__attribute__((address_space(3))) unsigned int*)(As + p_ * 8192 + 4096 + t * 8), 16, 0, 0); } while (0)

#define STAGE_B(X) do { const int p_ = (X) & 1;                                                \
    _Pragma("unroll")                                                                          \
    for (int j_ = 0; j_ < 4; ++j_)                                                             \
        __builtin_amdgcn_global_load_lds((const __attribute__((address_space(1))) unsigned int*) \
            (gB + (long)(j_ * 64) * K + (X) * 64),                                             \
            (__attribute__((address_space(3))) unsigned int*)(Bs + p_ * 16384 + j_ * 4096 + t * 8), 16, 0, 0); } while (0)

#define MIDSYNC() do {                                             \
    asm volatile("" ::: "memory");                                 \
    __builtin_amdgcn_s_barrier();                                  \
    asm volatile("s_waitcnt lgkmcnt(0)" ::: "memory");             \
    __builtin_amdgcn_sched_barrier(0); } while (0)

#define ENDBAR() do {                                              \
    asm volatile("" ::: "memory");                                 \
    __builtin_amdgcn_s_barrier(); } while (0)

#define MFMA_Q(BCOL, BR) do {                                      \
    __builtin_amdgcn_s_setprio(1);                                 \
    _Pragma("unroll")                                              \
    for (int ks = 0; ks < 2; ++ks)                                 \
        _Pragma("unroll")                                          \
        for (int m = 0; m < 4; ++m)                                \
            _Pragma("unroll")                                      \
            for (int n = 0; n < 2; ++n)                            \
                acc[m][(BCOL) + n] =                               \
                    __builtin_amdgcn_mfma_f32_16x16x32_bf16(ar[m][ks], (BR)[n][ks], acc[m][(BCOL) + n], 0, 0, 0); \
    __builtin_amdgcn_s_setprio(0); } while (0)

#define KTILE(U, BUF) do {                                                                     \
    const int Asb = (BUF) * 8192 + wr * 4096;                                                  \
    const int Bcb = (BUF) * 16384 + wc * 4096;                                                 \
    _Pragma("unroll")                                                                          \
    for (int m = 0; m < 4; ++m)                                                                \
        _Pragma("unroll")                                                                      \
        for (int ks = 0; ks < 2; ++ks)                                                         \
            ar[m][ks] = *reinterpret_cast<const short8*>(&As[Asb + m * 1024 + aoffE[ks]]);     \
    _Pragma("unroll")                                                                          \
    for (int n = 0; n < 2; ++n)                                                                \
        _Pragma("unroll")                                                                      \
        for (int ks = 0; ks < 2; ++ks)                                                         \
            br0[n][ks] = *reinterpret_cast<const short8*>(&Bs[Bcb + n * 1024 + aoffE[ks]]);    \
    MIDSYNC();                                                                                 \
    MFMA_Q(0, br0);                                                                            \
    ENDBAR();                                                                                  \
    _Pragma("unroll")                                                                          \
    for (int n = 0; n < 2; ++n)                                                                \
        _Pragma("unroll")                                                                      \
        for (int ks = 0; ks < 2; ++ks)                                                         \
            br1[n][ks] = *reinterpret_cast<const short8*>(&Bs[Bcb + 2048 + n * 1024 + aoffE[ks]]); \
    if ((U) + 2 < nt) STAGE_A((U) + 2);                                                        \
    MIDSYNC();                                                                                 \
    MFMA_Q(2, br1);                                                                            \
    if ((U) + 2 < nt) STAGE_B((U) + 2);                                                        \
    asm volatile("" ::: "memory");                                                             \
    if ((U) < nt - 2) {                                                                        \
        asm volatile("s_waitcnt vmcnt(6)" ::: "memory");                                       \
    } else if ((U) == nt - 2) {                                                                \
        asm volatile("s_waitcnt vmcnt(0)" ::: "memory");                                       \
    }                                                                                          \
    __builtin_amdgcn_s_barrier(); } while (0)

    STAGE_A(0); STAGE_B(0); STAGE_A(1); STAGE_B(1);
    asm volatile("s_waitcnt vmcnt(6)" ::: "memory");
    __builtin_amdgcn_s_barrier();

    short8 ar[4][2], br0[2][2], br1[2][2];

    for (int U = 0; U < nt; U += 2) {
        KTILE(U, 0);
        KTILE(U + 1, 1);
    }
#undef KTILE
#undef MFMA_Q
#undef ENDBAR
#undef MIDSYNC
#undef STAGE_A
#undef STAGE_B

    const int S = 2048;
    #pragma unroll
    for (int m = 0; m < 4; ++m) {
        #pragma unroll
        for (int n = 0; n < 4; ++n) {
            const int col = n0 + wc * 64 + n * 16 + lr;
            const int rowb = m0 + wr * 64 + m * 16 + lg * 4;
            if (EPI == 0) {
                #pragma unroll
                for (int r = 0; r < 4; ++r)
                    ((float*)Cout)[(long)(rowb + r) * N + col] = acc[m][n][r];
            } else {
                const int which = col >> 11;          // block-uniform (2048 % 256 == 0)
                const int h = (col >> 7) & 15;
                const int d = col & 127;
                const int bb = rowb >> 11;
                const int sb = rowb & 2047;
                if (which == 2) {
                    short4v o;
                    #pragma unroll
                    for (int r = 0; r < 4; ++r) o[r] = (short)f2bf(acc[m][n][r]);
                    *reinterpret_cast<short4v*>(Vt + ((long)(bb * 16 + h) * 128 + d) * S + sb) = o;
                } else {
                    const int i0 = d >> 1;
                    const float qs = (which == 0) ? QK_LOG2E_SCALE : 1.0f;
                    #pragma unroll
                    for (int r = 0; r < 4; ++r) {
                        const int s = sb + r;
                        float v = acc[m][n][r];
                        float p = __shfl_xor(v, 1);
                        float2 cs = fcs[(long)s * 64 + i0];
                        float o = (lr & 1) ? (p * cs.y + v * cs.x) : (v * cs.x - p * cs.y);
                        ((ushort_t*)Cout)[(long)which * M * 2048 +
                                          (((long)(bb * 16 + h)) * 2048 + s) * 128 + d] = f2bf(o * qs);
                    }
                }
            }
        }
    }
}

// ---------------- causal flash attention (XCD-affinity: all q-blocks of a head on one XCD) ----------------
// 1D grid of 512: slot -> xcd = slot&7, idx = slot>>3; bh = xcd + 8*(idx>>4), fold = idx&15.
// Each XCD serves 4 heads x 1MB K/V = 4MB (== its L2), 16 sharer-blocks hit L2-warm lines.
__global__ __launch_bounds__(256, 3) void attn_kernel(const ushort_t* __restrict__ Qp,
                                                      const ushort_t* __restrict__ Kp,
                                                      const ushort_t* __restrict__ Vtg,
                                                      ushort_t* __restrict__ O,
                                                      int S, int H) {
    __shared__ __align__(16) ushort_t Ks[64 * 128];   // linear, XOR-swizzled 16B slots
    __shared__ __align__(16) ushort_t Vs[128 * 64];   // linear, XOR-swizzled 16B slots
    __shared__ __align__(16) ushort_t Pl[4][16][72];
    const int t = threadIdx.x, wid = t >> 6, lane = t & 63;
    const int lr = lane & 15, lg = lane >> 4;

    const int slot = blockIdx.x;
    const int xcd = slot & 7;
    const int idx = slot >> 3;            // 0..63
    const int bh = xcd + 8 * (idx >> 4);  // 4 heads per XCD
    const int fold = idx & 15;            // 16 folded q-pairs per head

    const int b = bh / H, h = bh % H;
    const ushort_t* Qh = Qp + (long)bh * S * 128;
    const ushort_t* Kh = Kp + (long)bh * S * 128;
    const ushort_t* Vth = Vtg + (long)bh * 128 * S;
    const int nq = S / 64;

    const int ksr = t >> 2;
    const int vsr = t & 127;
    const int vsc = (t >> 7) * 32;

    for (int qsel = 0; qsel < 2; ++qsel) {
        const int qt = qsel ? (nq - 1 - fold) : fold;
        const int qb0 = qt * 64;

        const int qrow = qb0 + wid * 16 + lr;
        short8 qf[4];
        #pragma unroll
        for (int kk = 0; kk < 4; ++kk)
            qf[kk] = *reinterpret_cast<const short8*>(Qh + (long)qrow * 128 + kk * 32 + lg * 8);

        f32x4 oacc[8] = {};
        float mrow[4], lsum[4];
        #pragma unroll
        for (int r = 0; r < 4; ++r) { mrow[r] = -INFINITY; lsum[r] = 0.f; }

        const int nkt = qt + 1;

        short8 kreg[4], vreg[4];
        {
            const ushort_t* kgp = Kh + t * 32;
            const ushort_t* vgp = Vth + (long)vsr * S + vsc;
            #pragma unroll
            for (int j = 0; j < 4; ++j) kreg[j] = *reinterpret_cast<const short8*>(kgp + j * 8);
            #pragma unroll
            for (int j = 0; j < 4; ++j) vreg[j] = *reinterpret_cast<const short8*>(vgp + j * 8);
        }

        for (int kt = 0; kt < nkt; ++kt) {
            const int kv0 = kt * 64;
            __syncthreads();
            #pragma unroll
            for (int j = 0; j < 4; ++j)
                *reinterpret_cast<short8*>(&Ks[(ksr << 7) + (((((t & 3) << 2) + j) ^ (ksr & 7)) << 3)]) = kreg[j];
            #pragma unroll
            for (int j = 0; j < 4; ++j)
                *reinterpret_cast<short8*>(&Vs[(vsr << 6) + (((((t >> 7) << 2) + j) ^ (vsr & 7)) << 3)]) = vreg[j];
            __syncthreads();
            if (kt + 1 < nkt) {
                const ushort_t* kgp = Kh + (long)(kv0 + 64) * 128 + t * 32;
                const ushort_t* vgp = Vth + (long)vsr * S + kv0 + 64 + vsc;
                #pragma unroll
                for (int j = 0; j < 4; ++j) kreg[j] = *reinterpret_cast<const short8*>(kgp + j * 8);
                #pragma unroll
                for (int j = 0; j < 4; ++j) vreg[j] = *reinterpret_cast<const short8*>(vgp + j * 8);
            }

            f32x4 sacc[4] = {};
            #pragma unroll
            for (int kk = 0; kk < 4; ++kk) {
                #pragma unroll
                for (int n = 0; n < 4; ++n) {
                    short8 kf = *reinterpret_cast<const short8*>(
                        &Ks[((n * 16 + lr) << 7) + ((((kk << 2) + lg) ^ (lr & 7)) << 3)]);
                    sacc[n] = __builtin_amdgcn_mfma_f32_16x16x32_bf16(qf[kk], kf, sacc[n], 0, 0, 0);
                }
            }
            // Q pre-scaled by scale*log2e -> base-2 softmax via raw v_exp_f32.
            float sv[4][4];
            if (kt == qt) {
                const int myq = qb0 + wid * 16 + lg * 4;
                #pragma unroll
                for (int n = 0; n < 4; ++n) {
                    int kcol = kv0 + n * 16 + lr;
                    #pragma unroll
                    for (int r = 0; r < 4; ++r)
                        sv[n][r] = (kcol > myq + r) ? -1e9f : sacc[n][r];
                }
            } else {
                #pragma unroll
                for (int n = 0; n < 4; ++n)
                    #pragma unroll
                    for (int r = 0; r < 4; ++r)
                        sv[n][r] = sacc[n][r];
            }
            float alpha[4];
            #pragma unroll
            for (int r = 0; r < 4; ++r) {
                float mx = fmaxf(fmaxf(sv[0][r], sv[1][r]), fmaxf(sv[2][r], sv[3][r]));
                #pragma unroll
                for (int off = 1; off < 16; off <<= 1)
                    mx = fmaxf(mx, __shfl_xor(mx, off));
                float mnew = fmaxf(mrow[r], mx);
                alpha[r] = __builtin_amdgcn_exp2f(mrow[r] - mnew);
                float ts = 0.f;
                #pragma unroll
                for (int n = 0; n < 4; ++n) {
                    float p = __builtin_amdgcn_exp2f(sv[n][r] - mnew);
                    sv[n][r] = p;
                    ts += p;
                }
                #pragma unroll
                for (int off = 1; off < 16; off <<= 1)
                    ts += __shfl_xor(ts, off);
                lsum[r] = lsum[r] * alpha[r] + ts;
                mrow[r] = mnew;
            }
            #pragma unroll
            for (int f = 0; f < 8; ++f)
                #pragma unroll
                for (int r = 0; r < 4; ++r)
                    oacc[f][r] *= alpha[r];
            #pragma unroll
            for (int n = 0; n < 4; ++n)
                #pragma unroll
                for (int r = 0; r < 4; ++r)
                    Pl[wid][lg * 4 + r][n * 16 + lr] = f2bf(sv[n][r]);
            __asm volatile("" ::: "memory");
            short8 pf[2];
            #pragma unroll
            for (int ks = 0; ks < 2; ++ks)
                pf[ks] = *reinterpret_cast<const short8*>(&Pl[wid][lr][ks * 32 + lg * 8]);
            #pragma unroll
            for (int ks = 0; ks < 2; ++ks) {
                #pragma unroll
                for (int f = 0; f < 8; ++f) {
                    short8 vf = *reinterpret_cast<const short8*>(
                        &Vs[((f * 16 + lr) << 6) + ((((ks << 2) + lg) ^ (lr & 7)) << 3)]);
                    oacc[f] = __builtin_amdgcn_mfma_f32_16x16x32_bf16(pf[ks], vf, oacc[f], 0, 0, 0);
                }
            }
        }
        float inv[4];
        #pragma unroll
        for (int r = 0; r < 4; ++r) inv[r] = 1.f / lsum[r];
        ushort_t* Oh = O + (long)b * S * 2048 + h * 128;
        #pragma unroll
        for (int f = 0; f < 8; ++f) {
            #pragma unroll
            for (int r = 0; r < 4; ++r) {
                int row = qb0 + wid * 16 + lg * 4 + r;
                int col = f * 16 + lr;
                Oh[(long)row * 2048 + col] = f2bf(oacc[f][r] * inv[r]);
            }
        }
    }
}

extern "C" void kernel_launch(void* const* d_in, const int* in_sizes, int n_in,
                              void* d_out, int out_size, void* d_ws, size_t ws_size,
                              hipStream_t stream) {
    const float* x  = (const float*)d_in[0];
    const float* fc = (const float*)d_in[1];
    const float* fs = (const float*)d_in[2];
    const float* wq = (const float*)d_in[3];
    const float* wk = (const float*)d_in[4];
    const float* wv = (const float*)d_in[5];
    const float* wo = (const float*)d_in[6];
    float* out = (float*)d_out;

    const int B = 2, S = 2048, D = 2048, H = 16;
    const int M = B * S;            // 4096
    const size_t MD = (size_t)M * D;
    const size_t DD = (size_t)D * D;

    char* ws = (char*)d_ws;
    ushort_t* xbf = (ushort_t*)ws;                  // A input; attnb overlay after GEMM
    ushort_t* wqb = (ushort_t*)(ws + MD * 2);       // wq|wk|wv|wo bf16 contiguous
    ushort_t* wob = wqb + 3 * DD;
    ushort_t* qp  = wqb + 4 * DD;                   // Q packed [bh,s,128] (pre-scaled)
    ushort_t* kp  = qp + MD;                        // K packed
    ushort_t* vtg = kp + MD;                        // V transposed [bh,128,s]
    float2* fcs   = (float2*)(vtg + MD);            // packed (cos,sin) table, 1MB
    ushort_t* attnb = xbf;                          // overlay: x dead after QKV GEMM

    // 1) fused convert + rope table
    const int npair4 = S * 64 / 4;   // 32768
    cvt_all<<<2048, 256, 0, stream>>>(x, wq, wk, wv, wo, fc, fs, xbf, fcs,
                                      (int)(MD / 8), (int)(DD / 8), npair4);

    // 2) fused QKV projection (128x256 tile, 768 blocks = 3 exact generations)
    dim3 gq(6144 / 256, M / 128);
    gemm_wide<1><<<gq, 512, 98304, stream>>>(xbf, wqb, qp, vtg, fcs, M, 3 * D, D);

    // 3) causal flash attention (XCD-affinity 1D grid)
    const int nblk = (S / 128) * (B * H);   // 512
    attn_kernel<<<nblk, 256, 0, stream>>>(qp, kp, vtg, attnb, S, H);

    // 4) output projection (fp32 out): 256 blocks = exactly 1 full generation
    dim3 gg(D / 256, M / 128);
    gemm_wide<0><<<gg, 512, 98304, stream>>>(attnb, wob, out, nullptr, nullptr, M, D, D);
}

// Round 15
// 267.604 us; speedup vs baseline: 1.1571x; 1.0825x over previous
//
#include <hip/hip_runtime.h>
#include <hip/hip_bf16.h>
#include <math.h>

typedef __attribute__((ext_vector_type(8))) short short8;
typedef __attribute__((ext_vector_type(4))) short short4v;
typedef __attribute__((ext_vector_type(4))) float f32x4;
typedef unsigned short ushort_t;

// scale(1/sqrt(128)) * log2(e): folded into Q so attn softmax uses exp2 with no mults
#define QK_LOG2E_SCALE 0.1275274059009601f

__device__ __forceinline__ ushort_t f2bf(float f) {
    union { float f; unsigned u; } v; v.f = f;
    unsigned r = v.u + 0x7FFF + ((v.u >> 16) & 1);
    return (ushort_t)(r >> 16);
}

// ---- fused convert: x|wq|wk|wv|wo -> bf16, plus packed float2 (cos,sin) table ----
__global__ void cvt_all(const float* __restrict__ x,
                        const float* __restrict__ w0, const float* __restrict__ w1,
                        const float* __restrict__ w2, const float* __restrict__ w3,
                        const float* __restrict__ fc, const float* __restrict__ fs,
                        ushort_t* __restrict__ dst, float2* __restrict__ fcs,
                        int md8, int dd8, int npair4) {
    int i = blockIdx.x * blockDim.x + threadIdx.x;
    int stride = gridDim.x * blockDim.x;
    const int total0 = md8 + 4 * dd8;
    const int total = total0 + npair4;
    for (; i < total; i += stride) {
        if (i < total0) {
            const float* src;
            long off;
            if (i < md8) { src = x; off = i; }
            else {
                int j = i - md8;
                int which = j / dd8;
                off = j - (long)which * dd8;
                src = (which == 0) ? w0 : (which == 1) ? w1 : (which == 2) ? w2 : w3;
            }
            const float4* s = reinterpret_cast<const float4*>(src) + off * 2;
            float4 a = s[0], b = s[1];
            short8 o;
            o[0] = (short)f2bf(a.x); o[1] = (short)f2bf(a.y);
            o[2] = (short)f2bf(a.z); o[3] = (short)f2bf(a.w);
            o[4] = (short)f2bf(b.x); o[5] = (short)f2bf(b.y);
            o[6] = (short)f2bf(b.z); o[7] = (short)f2bf(b.w);
            reinterpret_cast<short8*>(dst)[i] = o;
        } else {
            int j = i - total0;
            float4 c4 = reinterpret_cast<const float4*>(fc)[j];
            float4 s4 = reinterpret_cast<const float4*>(fs)[j];
            float2* o = fcs + (long)j * 4;
            o[0] = make_float2(c4.x, s4.x);
            o[1] = make_float2(c4.y, s4.y);
            o[2] = make_float2(c4.z, s4.z);
            o[3] = make_float2(c4.w, s4.w);
        }
    }
}

// ============ 128x256 2-phase-per-K-tile GEMM: BK=64, 8 waves, counted vmcnt ============
// EPI=1: fused RoPE/transposed-V QKV epilogue (bf16). EPI=0: plain fp32 [M,N] out (wo).
template<int EPI>
__global__ __launch_bounds__(512, 2) void gemm_wide(const ushort_t* __restrict__ A,
                                                    const ushort_t* __restrict__ Bw,
                                                    void* __restrict__ Cout,
                                                    ushort_t* __restrict__ Vt,
                                                    const float2* __restrict__ fcs,
                                                    int M, int N, int K) {
    extern __shared__ __align__(16) ushort_t lds[];
    ushort_t* As = lds;              // 16384 elems (32KB)
    ushort_t* Bs = lds + 16384;      // 32768 elems (64KB)
    const int t = threadIdx.x;
    const int wid = t >> 6, lane = t & 63;
    const int wr = wid >> 2, wc = wid & 3;     // 2 row-waves x 4 col-waves
    const int lr = lane & 15, lg = lane >> 4;

    const int ntc = N >> 8;
    const int nwg = (M >> 7) * ntc;
    const int bid = blockIdx.y * gridDim.x + blockIdx.x;
    const int cpx = nwg >> 3;
    const int swz = (bid & 7) * cpx + (bid >> 3);
    const int m0 = (swz / ntc) * 128, n0 = (swz % ntc) * 256;

    f32x4 acc[4][4] = {};

    const int r0 = t >> 3;
    const int c0 = (t & 7) ^ (r0 & 7);
    const ushort_t* gA = A + (long)(m0 + r0) * K + c0 * 8;
    const ushort_t* gB = Bw + (long)(n0 + r0) * K + c0 * 8;

    int aoffE[2];
    aoffE[0] = lr * 64 + (((0 + lg) ^ (lr & 7)) << 3);
    aoffE[1] = lr * 64 + (((4 + lg) ^ (lr & 7)) << 3);

    const int nt = K >> 6;   // 32 (even)

#define STAGE_A(X) do { const int p_ = (X) & 1;                                                \
    __builtin_amdgcn_global_load_lds((const __attribute__((address_space(1))) unsigned int*)   \
        (gA + (X) * 64),                                                                       \
        (__attribute__((address_space(3))) unsigned int*)(As + p_ * 8192 + t * 8), 16, 0, 0);  \
    __builtin_amdgcn_global_load_lds((const __attribute__((address_space(1))) unsigned int*)   \
        (gA + (long)64 * K + (X) * 64),                                                        \
        (__attribute__((address_space(3))) unsigned int*)(As + p_ * 8192 + 4096 + t * 8), 16, 0, 0); } while (0)

#define STAGE_B(X) do { const int p_ = (X) & 1;                                                \
    _Pragma("unroll")                                                                          \
    for (int j_ = 0; j_ < 4; ++j_)                                                             \
        __builtin_amdgcn_global_load_lds((const __attribute__((address_space(1))) unsigned int*) \
            (gB + (long)(j_ * 64) * K + (X) * 64),                                             \
            (__attribute__((address_space(3))) unsigned int*)(Bs + p_ * 16384 + j_ * 4096 + t * 8), 16, 0, 0); } while (0)

#define MIDSYNC() do {                                             \
    asm volatile("" ::: "memory");                                 \
    __builtin_amdgcn_s_barrier();                                  \
    asm volatile("s_waitcnt lgkmcnt(0)" ::: "memory");             \
    __builtin_amdgcn_sched_barrier(0); } while (0)

#define ENDBAR() do {                                              \
    asm volatile("" ::: "memory");                                 \
    __builtin_amdgcn_s_barrier(); } while (0)

#define MFMA_Q(BCOL, BR) do {                                      \
    __builtin_amdgcn_s_setprio(1);                                 \
    _Pragma("unroll")                                              \
    for (int ks = 0; ks < 2; ++ks)                                 \
        _Pragma("unroll")                                          \
        for (int m = 0; m < 4; ++m)                                \
            _Pragma("unroll")                                      \
            for (int n = 0; n < 2; ++n)                            \
                acc[m][(BCOL) + n] =                               \
                    __builtin_amdgcn_mfma_f32_16x16x32_bf16(ar[m][ks], (BR)[n][ks], acc[m][(BCOL) + n], 0, 0, 0); \
    __builtin_amdgcn_s_setprio(0); } while (0)

#define KTILE(U, BUF) do {                                                                     \
    const int Asb = (BUF) * 8192 + wr * 4096;                                                  \
    const int Bcb = (BUF) * 16384 + wc * 4096;                                                 \
    _Pragma("unroll")                                                                          \
    for (int m = 0; m < 4; ++m)                                                                \
        _Pragma("unroll")                                                                      \
        for (int ks = 0; ks < 2; ++ks)                                                         \
            ar[m][ks] = *reinterpret_cast<const short8*>(&As[Asb + m * 1024 + aoffE[ks]]);     \
    _Pragma("unroll")                                                                          \
    for (int n = 0; n < 2; ++n)                                                                \
        _Pragma("unroll")                                                                      \
        for (int ks = 0; ks < 2; ++ks)                                                         \
            br0[n][ks] = *reinterpret_cast<const short8*>(&Bs[Bcb + n * 1024 + aoffE[ks]]);    \
    MIDSYNC();                                                                                 \
    MFMA_Q(0, br0);                                                                            \
    ENDBAR();                                                                                  \
    _Pragma("unroll")                                                                          \
    for (int n = 0; n < 2; ++n)                                                                \
        _Pragma("unroll")                                                                      \
        for (int ks = 0; ks < 2; ++ks)                                                         \
            br1[n][ks] = *reinterpret_cast<const short8*>(&Bs[Bcb + 2048 + n * 1024 + aoffE[ks]]); \
    if ((U) + 2 < nt) STAGE_A((U) + 2);                                                        \
    MIDSYNC();                                                                                 \
    MFMA_Q(2, br1);                                                                            \
    if ((U) + 2 < nt) STAGE_B((U) + 2);                                                        \
    asm volatile("" ::: "memory");                                                             \
    if ((U) < nt - 2) {                                                                        \
        asm volatile("s_waitcnt vmcnt(6)" ::: "memory");                                       \
    } else if ((U) == nt - 2) {                                                                \
        asm volatile("s_waitcnt vmcnt(0)" ::: "memory");                                       \
    }                                                                                          \
    __builtin_amdgcn_s_barrier(); } while (0)

    STAGE_A(0); STAGE_B(0); STAGE_A(1); STAGE_B(1);
    asm volatile("s_waitcnt vmcnt(6)" ::: "memory");
    __builtin_amdgcn_s_barrier();

    short8 ar[4][2], br0[2][2], br1[2][2];

    for (int U = 0; U < nt; U += 2) {
        KTILE(U, 0);
        KTILE(U + 1, 1);
    }
#undef KTILE
#undef MFMA_Q
#undef ENDBAR
#undef MIDSYNC
#undef STAGE_A
#undef STAGE_B

    const int S = 2048;
    #pragma unroll
    for (int m = 0; m < 4; ++m) {
        #pragma unroll
        for (int n = 0; n < 4; ++n) {
            const int col = n0 + wc * 64 + n * 16 + lr;
            const int rowb = m0 + wr * 64 + m * 16 + lg * 4;
            if (EPI == 0) {
                #pragma unroll
                for (int r = 0; r < 4; ++r)
                    ((float*)Cout)[(long)(rowb + r) * N + col] = acc[m][n][r];
            } else {
                const int which = col >> 11;          // block-uniform (2048 % 256 == 0)
                const int h = (col >> 7) & 15;
                const int d = col & 127;
                const int bb = rowb >> 11;
                const int sb = rowb & 2047;
                if (which == 2) {
                    short4v o;
                    #pragma unroll
                    for (int r = 0; r < 4; ++r) o[r] = (short)f2bf(acc[m][n][r]);
                    *reinterpret_cast<short4v*>(Vt + ((long)(bb * 16 + h) * 128 + d) * S + sb) = o;
                } else {
                    const int i0 = d >> 1;
                    const float qs = (which == 0) ? QK_LOG2E_SCALE : 1.0f;
                    #pragma unroll
                    for (int r = 0; r < 4; ++r) {
                        const int s = sb + r;
                        float v = acc[m][n][r];
                        float p = __shfl_xor(v, 1);
                        float2 cs = fcs[(long)s * 64 + i0];
                        float o = (lr & 1) ? (p * cs.y + v * cs.x) : (v * cs.x - p * cs.y);
                        ((ushort_t*)Cout)[(long)which * M * 2048 +
                                          (((long)(bb * 16 + h)) * 2048 + s) * 128 + d] = f2bf(o * qs);
                    }
                }
            }
        }
    }
}

// ---------------- causal flash attention: merged-fold, one kv sweep per block ----------------
// Block handles q-tiles qt1=fold and qt2=31-fold in ONE kv sweep 0..qt2:
// q2 computes every tile, q1 only while kt<=qt1. Staged tiles 33 -> 32-fold (avg -26%),
// total MFMA per block unchanged (uniform 33 tile-units). XCD-affinity grid as r14.
__global__ __launch_bounds__(256, 2) void attn_kernel(const ushort_t* __restrict__ Qp,
                                                      const ushort_t* __restrict__ Kp,
                                                      const ushort_t* __restrict__ Vtg,
                                                      ushort_t* __restrict__ O,
                                                      int S, int H) {
    __shared__ __align__(16) ushort_t Ks[64 * 128];   // linear, XOR-swizzled 16B slots
    __shared__ __align__(16) ushort_t Vs[128 * 64];   // linear, XOR-swizzled 16B slots
    __shared__ __align__(16) ushort_t Pl[4][16][72];
    const int t = threadIdx.x, wid = t >> 6, lane = t & 63;
    const int lr = lane & 15, lg = lane >> 4;

    const int slot = blockIdx.x;
    const int xcd = slot & 7;
    const int idx = slot >> 3;            // 0..63
    const int bh = xcd + 8 * (idx >> 4);  // 4 heads per XCD
    const int fold = idx & 15;

    const int b = bh / H, h = bh % H;
    const ushort_t* Qh = Qp + (long)bh * S * 128;
    const ushort_t* Kh = Kp + (long)bh * S * 128;
    const ushort_t* Vth = Vtg + (long)bh * 128 * S;
    const int nq = S / 64;                // 32
    const int qt1 = fold, qt2 = nq - 1 - fold;
    const int qb1 = qt1 * 64, qb2 = qt2 * 64;

    const int ksr = t >> 2;
    const int vsr = t & 127;
    const int vsc = (t >> 7) * 32;

    // Q fragments for both tiles
    short8 qf1[4], qf2[4];
    {
        const int qr1 = qb1 + wid * 16 + lr;
        const int qr2 = qb2 + wid * 16 + lr;
        #pragma unroll
        for (int kk = 0; kk < 4; ++kk) {
            qf1[kk] = *reinterpret_cast<const short8*>(Qh + (long)qr1 * 128 + kk * 32 + lg * 8);
            qf2[kk] = *reinterpret_cast<const short8*>(Qh + (long)qr2 * 128 + kk * 32 + lg * 8);
        }
    }

    f32x4 oacc1[8] = {}, oacc2[8] = {};
    float mrow1[4], lsum1[4], mrow2[4], lsum2[4];
    #pragma unroll
    for (int r = 0; r < 4; ++r) {
        mrow1[r] = -INFINITY; lsum1[r] = 0.f;
        mrow2[r] = -INFINITY; lsum2[r] = 0.f;
    }

    // per-tile compute for one q-stream (inlined twice per iteration)
    auto tile_compute = [&](const short8* qf, f32x4* oacc, float* mrow, float* lsum,
                            int qb0, bool diag, int kv0) {
        f32x4 sacc[4] = {};
        #pragma unroll
        for (int kk = 0; kk < 4; ++kk) {
            #pragma unroll
            for (int n = 0; n < 4; ++n) {
                short8 kf = *reinterpret_cast<const short8*>(
                    &Ks[((n * 16 + lr) << 7) + ((((kk << 2) + lg) ^ (lr & 7)) << 3)]);
                sacc[n] = __builtin_amdgcn_mfma_f32_16x16x32_bf16(qf[kk], kf, sacc[n], 0, 0, 0);
            }
        }
        float sv[4][4];
        if (diag) {
            const int myq = qb0 + wid * 16 + lg * 4;
            #pragma unroll
            for (int n = 0; n < 4; ++n) {
                int kcol = kv0 + n * 16 + lr;
                #pragma unroll
                for (int r = 0; r < 4; ++r)
                    sv[n][r] = (kcol > myq + r) ? -1e9f : sacc[n][r];
            }
        } else {
            #pragma unroll
            for (int n = 0; n < 4; ++n)
                #pragma unroll
                for (int r = 0; r < 4; ++r)
                    sv[n][r] = sacc[n][r];
        }
        float alpha[4];
        #pragma unroll
        for (int r = 0; r < 4; ++r) {
            float mx = fmaxf(fmaxf(sv[0][r], sv[1][r]), fmaxf(sv[2][r], sv[3][r]));
            #pragma unroll
            for (int off = 1; off < 16; off <<= 1)
                mx = fmaxf(mx, __shfl_xor(mx, off));
            float mnew = fmaxf(mrow[r], mx);
            alpha[r] = __builtin_amdgcn_exp2f(mrow[r] - mnew);
            float ts = 0.f;
            #pragma unroll
            for (int n = 0; n < 4; ++n) {
                float p = __builtin_amdgcn_exp2f(sv[n][r] - mnew);
                sv[n][r] = p;
                ts += p;
            }
            #pragma unroll
            for (int off = 1; off < 16; off <<= 1)
                ts += __shfl_xor(ts, off);
            lsum[r] = lsum[r] * alpha[r] + ts;
            mrow[r] = mnew;
        }
        #pragma unroll
        for (int f = 0; f < 8; ++f)
            #pragma unroll
            for (int r = 0; r < 4; ++r)
                oacc[f][r] *= alpha[r];
        #pragma unroll
        for (int n = 0; n < 4; ++n)
            #pragma unroll
            for (int r = 0; r < 4; ++r)
                Pl[wid][lg * 4 + r][n * 16 + lr] = f2bf(sv[n][r]);
        __asm volatile("" ::: "memory");
        short8 pf[2];
        #pragma unroll
        for (int ks = 0; ks < 2; ++ks)
            pf[ks] = *reinterpret_cast<const short8*>(&Pl[wid][lr][ks * 32 + lg * 8]);
        #pragma unroll
        for (int ks = 0; ks < 2; ++ks) {
            #pragma unroll
            for (int f = 0; f < 8; ++f) {
                short8 vf = *reinterpret_cast<const short8*>(
                    &Vs[((f * 16 + lr) << 6) + ((((ks << 2) + lg) ^ (lr & 7)) << 3)]);
                oacc[f] = __builtin_amdgcn_mfma_f32_16x16x32_bf16(pf[ks], vf, oacc[f], 0, 0, 0);
            }
        }
        __asm volatile("" ::: "memory");   // Pl reuse by second stream: order write-after-read
    };

    short8 kreg[4], vreg[4];
    {
        const ushort_t* kgp = Kh + t * 32;
        const ushort_t* vgp = Vth + (long)vsr * S + vsc;
        #pragma unroll
        for (int j = 0; j < 4; ++j) kreg[j] = *reinterpret_cast<const short8*>(kgp + j * 8);
        #pragma unroll
        for (int j = 0; j < 4; ++j) vreg[j] = *reinterpret_cast<const short8*>(vgp + j * 8);
    }

    for (int kt = 0; kt <= qt2; ++kt) {
        const int kv0 = kt * 64;
        __syncthreads();
        #pragma unroll
        for (int j = 0; j < 4; ++j)
            *reinterpret_cast<short8*>(&Ks[(ksr << 7) + (((((t & 3) << 2) + j) ^ (ksr & 7)) << 3)]) = kreg[j];
        #pragma unroll
        for (int j = 0; j < 4; ++j)
            *reinterpret_cast<short8*>(&Vs[(vsr << 6) + (((((t >> 7) << 2) + j) ^ (vsr & 7)) << 3)]) = vreg[j];
        __syncthreads();
        if (kt < qt2) {
            const ushort_t* kgp = Kh + (long)(kv0 + 64) * 128 + t * 32;
            const ushort_t* vgp = Vth + (long)vsr * S + kv0 + 64 + vsc;
            #pragma unroll
            for (int j = 0; j < 4; ++j) kreg[j] = *reinterpret_cast<const short8*>(kgp + j * 8);
            #pragma unroll
            for (int j = 0; j < 4; ++j) vreg[j] = *reinterpret_cast<const short8*>(vgp + j * 8);
        }

        tile_compute(qf2, oacc2, mrow2, lsum2, qb2, kt == qt2, kv0);
        if (kt <= qt1)
            tile_compute(qf1, oacc1, mrow1, lsum1, qb1, kt == qt1, kv0);
    }

    // epilogue: both q-tiles
    ushort_t* Oh = O + (long)b * S * 2048 + h * 128;
    {
        float inv[4];
        #pragma unroll
        for (int r = 0; r < 4; ++r) inv[r] = 1.f / lsum1[r];
        #pragma unroll
        for (int f = 0; f < 8; ++f)
            #pragma unroll
            for (int r = 0; r < 4; ++r) {
                int row = qb1 + wid * 16 + lg * 4 + r;
                Oh[(long)row * 2048 + f * 16 + lr] = f2bf(oacc1[f][r] * inv[r]);
            }
    }
    {
        float inv[4];
        #pragma unroll
        for (int r = 0; r < 4; ++r) inv[r] = 1.f / lsum2[r];
        #pragma unroll
        for (int f = 0; f < 8; ++f)
            #pragma unroll
            for (int r = 0; r < 4; ++r) {
                int row = qb2 + wid * 16 + lg * 4 + r;
                Oh[(long)row * 2048 + f * 16 + lr] = f2bf(oacc2[f][r] * inv[r]);
            }
    }
}

extern "C" void kernel_launch(void* const* d_in, const int* in_sizes, int n_in,
                              void* d_out, int out_size, void* d_ws, size_t ws_size,
                              hipStream_t stream) {
    const float* x  = (const float*)d_in[0];
    const float* fc = (const float*)d_in[1];
    const float* fs = (const float*)d_in[2];
    const float* wq = (const float*)d_in[3];
    const float* wk = (const float*)d_in[4];
    const float* wv = (const float*)d_in[5];
    const float* wo = (const float*)d_in[6];
    float* out = (float*)d_out;

    const int B = 2, S = 2048, D = 2048, H = 16;
    const int M = B * S;            // 4096
    const size_t MD = (size_t)M * D;
    const size_t DD = (size_t)D * D;

    char* ws = (char*)d_ws;
    ushort_t* xbf = (ushort_t*)ws;                  // A input; attnb overlay after GEMM
    ushort_t* wqb = (ushort_t*)(ws + MD * 2);       // wq|wk|wv|wo bf16 contiguous
    ushort_t* wob = wqb + 3 * DD;
    ushort_t* qp  = wqb + 4 * DD;                   // Q packed [bh,s,128] (pre-scaled)
    ushort_t* kp  = qp + MD;                        // K packed
    ushort_t* vtg = kp + MD;                        // V transposed [bh,128,s]
    float2* fcs   = (float2*)(vtg + MD);            // packed (cos,sin) table, 1MB
    ushort_t* attnb = xbf;                          // overlay: x dead after QKV GEMM

    // 1) fused convert + rope table
    const int npair4 = S * 64 / 4;   // 32768
    cvt_all<<<2048, 256, 0, stream>>>(x, wq, wk, wv, wo, fc, fs, xbf, fcs,
                                      (int)(MD / 8), (int)(DD / 8), npair4);

    // 2) fused QKV projection (128x256 tile, 768 blocks = 3 exact generations)
    dim3 gq(6144 / 256, M / 128);
    gemm_wide<1><<<gq, 512, 98304, stream>>>(xbf, wqb, qp, vtg, fcs, M, 3 * D, D);

    // 3) causal flash attention (merged-fold, XCD-affinity 1D grid)
    const int nblk = (S / 128) * (B * H);   // 512
    attn_kernel<<<nblk, 256, 0, stream>>>(qp, kp, vtg, attnb, S, H);

    // 4) output projection (fp32 out): 256 blocks = exactly 1 full generation
    dim3 gg(D / 256, M / 128);
    gemm_wide<0><<<gg, 512, 98304, stream>>>(attnb, wob, out, nullptr, nullptr, M, D, D);
}